// Round 3
// baseline (4488.094 us; speedup 1.0000x reference)
//
#include <hip/hip_runtime.h>
#include <cstdint>
#include <cstddef>

#define N_NODES 10000
#define N_EDGES 320000
#define N_GRAPHS 64
#define KCHEB 10
#define C_IN 128
#define C_HID 256
#define C_OUTC 128
#define POOL_CHUNK 40

static inline size_t align_up(size_t v, size_t a){ return (v + a - 1) / a * a; }

typedef __attribute__((ext_vector_type(8))) _Float16 half8;
typedef __attribute__((ext_vector_type(2))) _Float16 h2;
typedef __attribute__((ext_vector_type(4))) float f32x4;

// ---------------- graph setup kernels ----------------

__global__ void k_deg(const int* __restrict__ src, const int* __restrict__ dst,
                      int* __restrict__ deg, int* __restrict__ indeg){
  int e = blockIdx.x*blockDim.x + threadIdx.x;
  if(e < N_EDGES){
    atomicAdd(&deg[src[e]], 1);
    atomicAdd(&indeg[dst[e]], 1);
  }
}

__global__ void k_dis(const int* __restrict__ deg, float* __restrict__ dis){
  int i = blockIdx.x*blockDim.x + threadIdx.x;
  if(i < N_NODES){
    int d = deg[i];
    dis[i] = d > 0 ? rsqrtf((float)d) : 0.f;
  }
}

__global__ __launch_bounds__(1024) void k_scan(const int* __restrict__ cnt,
                                               int* __restrict__ offs,
                                               int* __restrict__ cursor){
  __shared__ int part[1024];
  const int n = N_NODES;
  const int CH = (n + 1023) / 1024;
  int tid = threadIdx.x;
  int base = tid * CH;
  int s = 0;
  for(int i = 0; i < CH; i++){
    int idx = base + i;
    if(idx < n) s += cnt[idx];
  }
  part[tid] = s;
  __syncthreads();
  for(int off = 1; off < 1024; off <<= 1){
    int v = (tid >= off) ? part[tid - off] : 0;
    __syncthreads();
    part[tid] += v;
    __syncthreads();
  }
  int run = (tid == 0) ? 0 : part[tid - 1];
  for(int i = 0; i < CH; i++){
    int idx = base + i;
    if(idx < n){
      offs[idx] = run;
      cursor[idx] = run;
      run += cnt[idx];
    }
  }
  if(tid == 1023) offs[n] = part[1023];
}

// scatter + edge-weight in one pass; weight stored as duplicated f16 pair
// (converted ONCE here instead of per edge per prop step).
__global__ void k_scatter(const int* __restrict__ src, const int* __restrict__ dst,
                          const float* __restrict__ dis, int* __restrict__ cursor,
                          int* __restrict__ csr_s, unsigned* __restrict__ csr_wp){
  int e = blockIdx.x*blockDim.x + threadIdx.x;
  if(e < N_EDGES){
    int s = src[e], d = dst[e];
    float w = -dis[s] * dis[d];
    unsigned short wb = __builtin_bit_cast(unsigned short, (_Float16)w);
    int p = atomicAdd(&cursor[d], 1);
    csr_s[p] = s;
    csr_wp[p] = (unsigned)wb * 0x00010001u;
  }
}

__global__ __launch_bounds__(128) void k_gbounds(const int* __restrict__ batch,
                                                 int* __restrict__ gstart,
                                                 int* __restrict__ gcnt){
  int g = threadIdx.x;
  if(g <= N_GRAPHS){
    int lo = 0, hi = N_NODES;
    while(lo < hi){
      int mid = (lo + hi) >> 1;
      if(batch[mid] < g) lo = mid + 1; else hi = mid;
    }
    gstart[g] = lo;
  }
  __syncthreads();
  if(g < N_GRAPHS) gcnt[g] = gstart[g + 1] - gstart[g];
}

// ---------------- device-scope grid barrier ----------------
// All blocks co-resident (guaranteed by __launch_bounds__(256,8): VGPR<=64 ->
// 8 blocks/CU -> capacity 2048 >= grid). Arrival = per-block flag store
// (parallel, no same-address atomic pileup); block 0 scans flags then sets the
// go word; others spin on go with RELAXED agent loads (reads LLC directly, no
// L2 invalidate per poll -> doesn't trash late blocks' L2 hits).
// __threadfence() release/acquire at the edges handles cross-XCD visibility.
__device__ inline void grid_barrier(int* flags, int* go, int nblocks, int phase){
  __syncthreads();
  __threadfence();   // release: wb dirty L2 so this block's tx writes reach LLC
  int tid = threadIdx.x;
  if(blockIdx.x == 0){
    if(tid == 0)
      __hip_atomic_store(&flags[0], phase, __ATOMIC_RELAXED, __HIP_MEMORY_SCOPE_AGENT);
    for(int i = tid; i < nblocks; i += 256){
      while(__hip_atomic_load(&flags[i], __ATOMIC_RELAXED, __HIP_MEMORY_SCOPE_AGENT) < phase)
        __builtin_amdgcn_s_sleep(2);
    }
    __syncthreads();
    if(tid == 0)
      __hip_atomic_store(go, phase, __ATOMIC_RELAXED, __HIP_MEMORY_SCOPE_AGENT);
  } else {
    if(tid == 0){
      __hip_atomic_store(&flags[blockIdx.x], phase, __ATOMIC_RELAXED, __HIP_MEMORY_SCOPE_AGENT);
      while(__hip_atomic_load(go, __ATOMIC_RELAXED, __HIP_MEMORY_SCOPE_AGENT) < phase)
        __builtin_amdgcn_s_sleep(4);
    }
    __syncthreads();
  }
  __threadfence();   // acquire: inv L1/L2 so next step reads fresh data
}

// ---------------- persistent propagation (f16, all 9 Cheb steps) ----------

__device__ inline void hfma4(h2* a, uint4 v, unsigned wbits){
  h2 w2 = __builtin_bit_cast(h2, wbits);
  a[0] += __builtin_bit_cast(h2, v.x) * w2;
  a[1] += __builtin_bit_cast(h2, v.y) * w2;
  a[2] += __builtin_bit_cast(h2, v.z) * w2;
  a[3] += __builtin_bit_cast(h2, v.w) * w2;
}

// 256-ch: channel-split halves pinned to XCD groups (bid%8 -> XCD), 16-lane
// groups own one node-half. Grid 1256 blocks, all co-resident.
__global__ __launch_bounds__(256, 8) void k_prop256_all(_Float16* __restrict__ base,
    const int* __restrict__ csr_s, const unsigned* __restrict__ csr_wp,
    const int* __restrict__ offs, int* __restrict__ flags, int* __restrict__ go){
  const int stride = KCHEB * C_HID, strideB = stride * 2;
  int bid  = blockIdx.x;
  int half = (bid >> 2) & 1;
  int lh   = (bid >> 3) * 4 + (bid & 3);
  int l15  = threadIdx.x & 15;
  int lane = threadIdx.x & 63;
  int b16  = lane & 48;
  int e8   = l15 & 7;
  int node = lh * 16 + (threadIdx.x >> 4);
  bool active = node < N_NODES;
  int j0 = 0, j1 = 0;
  if(active){ j0 = offs[node]; j1 = offs[node + 1]; }
  size_t noff = (size_t)node * stride + half * (C_HID / 2) + l15 * 8;
  const char* gb0 = (const char*)base + (half * (C_HID / 2) + l15 * 8) * 2;

  for(int k = 1; k < KCHEB; k++){
    if(active){
      const char* __restrict__ gbase = gb0 + (size_t)(k - 1) * C_HID * 2;
      h2 a[4] = {};
      int j = j0; int sv = 0; unsigned wv = 0;
      bool have = (j + 7 < j1);
      if(have){ sv = csr_s[j + e8] * strideB; wv = csr_wp[j + e8]; }
      while(have){
        int jn = j + 8;
        bool more = (jn + 7 < j1);
        int sv2 = 0; unsigned wv2 = 0;
        if(more){ sv2 = csr_s[jn + e8] * strideB; wv2 = csr_wp[jn + e8]; }
        uint4 v[8];
#pragma unroll
        for(int i = 0; i < 8; i++){
          int si = __shfl(sv, b16 + i);
          v[i] = *(const uint4*)(gbase + si);
        }
#pragma unroll
        for(int i = 0; i < 8; i++){
          unsigned wi = (unsigned)__shfl((int)wv, b16 + i);
          hfma4(a, v[i], wi);
        }
        sv = sv2; wv = wv2; j = jn; have = more;
      }
      for(; j < j1; j++){
        int si = csr_s[j] * strideB;
        uint4 v0 = *(const uint4*)(gbase + si);
        hfma4(a, v0, csr_wp[j]);
      }
      _Float16 ah = (k == 1) ? (_Float16)1.f : (_Float16)2.f;
      h2 al = {ah, ah};
      h2 r[4];
#pragma unroll
      for(int i = 0; i < 4; i++) r[i] = a[i] * al;
      if(k >= 2){
        const _Float16* Pb = base + (size_t)(k - 2) * C_HID;
        uint4 pv = *(const uint4*)(Pb + noff);
        r[0] -= __builtin_bit_cast(h2, pv.x);
        r[1] -= __builtin_bit_cast(h2, pv.y);
        r[2] -= __builtin_bit_cast(h2, pv.z);
        r[3] -= __builtin_bit_cast(h2, pv.w);
      }
      uint4 ob;
      ob.x = __builtin_bit_cast(unsigned, r[0]);
      ob.y = __builtin_bit_cast(unsigned, r[1]);
      ob.z = __builtin_bit_cast(unsigned, r[2]);
      ob.w = __builtin_bit_cast(unsigned, r[3]);
      *(uint4*)(base + (size_t)k * C_HID + noff) = ob;
    }
    if(k < KCHEB - 1) grid_barrier(flags, go, (int)gridDim.x, k);
  }
}

// 128-ch: 32-lane groups own one node. Grid 1250 blocks, all co-resident.
__global__ __launch_bounds__(256, 8) void k_prop128_all(_Float16* __restrict__ base,
    const int* __restrict__ csr_s, const unsigned* __restrict__ csr_wp,
    const int* __restrict__ offs, int* __restrict__ flags, int* __restrict__ go){
  const int stride = KCHEB * C_IN, strideB = stride * 2;
  int hl   = threadIdx.x & 31;
  int b32  = threadIdx.x & 32;
  int e8   = hl & 7;
  int node = blockIdx.x * 8 + (threadIdx.x >> 5);
  int j0 = offs[node], j1 = offs[node + 1];
  size_t noff = (size_t)node * stride + hl * 4;
  const char* gb0 = (const char*)base + hl * 8;

  for(int k = 1; k < KCHEB; k++){
    const char* __restrict__ gbase = gb0 + (size_t)(k - 1) * C_IN * 2;
    h2 a[2] = {};
    int j = j0; int sv = 0; unsigned wv = 0;
    bool have = (j + 7 < j1);
    if(have){ sv = csr_s[j + e8] * strideB; wv = csr_wp[j + e8]; }
    while(have){
      int jn = j + 8;
      bool more = (jn + 7 < j1);
      int sv2 = 0; unsigned wv2 = 0;
      if(more){ sv2 = csr_s[jn + e8] * strideB; wv2 = csr_wp[jn + e8]; }
      uint2 v[8];
#pragma unroll
      for(int i = 0; i < 8; i++){
        int si = __shfl(sv, b32 + i);
        v[i] = *(const uint2*)(gbase + si);
      }
#pragma unroll
      for(int i = 0; i < 8; i++){
        unsigned wi = (unsigned)__shfl((int)wv, b32 + i);
        h2 w2 = __builtin_bit_cast(h2, wi);
        a[0] += __builtin_bit_cast(h2, v[i].x) * w2;
        a[1] += __builtin_bit_cast(h2, v[i].y) * w2;
      }
      sv = sv2; wv = wv2; j = jn; have = more;
    }
    for(; j < j1; j++){
      int si = csr_s[j] * strideB;
      h2 w2 = __builtin_bit_cast(h2, csr_wp[j]);
      uint2 v0 = *(const uint2*)(gbase + si);
      a[0] += __builtin_bit_cast(h2, v0.x) * w2;
      a[1] += __builtin_bit_cast(h2, v0.y) * w2;
    }
    _Float16 ah = (k == 1) ? (_Float16)1.f : (_Float16)2.f;
    h2 al = {ah, ah};
    h2 r0 = a[0] * al, r1 = a[1] * al;
    if(k >= 2){
      const _Float16* Pb = base + (size_t)(k - 2) * C_IN;
      uint2 pv = *(const uint2*)(Pb + noff);
      r0 -= __builtin_bit_cast(h2, pv.x);
      r1 -= __builtin_bit_cast(h2, pv.y);
    }
    uint2 ob;
    ob.x = __builtin_bit_cast(unsigned, r0);
    ob.y = __builtin_bit_cast(unsigned, r1);
    *(uint2*)(base + (size_t)k * C_IN + noff) = ob;
    if(k < KCHEB - 1) grid_barrier(flags, go, (int)gridDim.x, k);
  }
}

// fp32 [rows][C] -> f16 strided slot (layer-1 input only)
template<int C>
__global__ void k_f2h(const float* __restrict__ X, _Float16* __restrict__ tx,
                      int tx_stride){
  int idx = blockIdx.x * blockDim.x + threadIdx.x;
  const int GPR = C / 4;
  if(idx < N_NODES * GPR){
    int r = idx / GPR;
    int c = (idx - r * GPR) * 4;
    float4 v = *(const float4*)(X + (size_t)r * C + c);
    h2 p0 = {(_Float16)v.x, (_Float16)v.y};
    h2 p1 = {(_Float16)v.z, (_Float16)v.w};
    uint2 ob;
    ob.x = __builtin_bit_cast(unsigned, p0);
    ob.y = __builtin_bit_cast(unsigned, p1);
    *(uint2*)(tx + (size_t)r * tx_stride + c) = ob;
  }
}

// LDS-tiled weight transpose (old version read stride-1KB, fully uncoalesced):
// WT[o][kc] = (f16)W[kc][o], W is [R][256], R in {1280,2560,2560}.
__global__ __launch_bounds__(256) void k_wt3t(const float* __restrict__ W0, _Float16* __restrict__ WT0,
                                              const float* __restrict__ W1, _Float16* __restrict__ WT1,
                                              const float* __restrict__ W2, _Float16* __restrict__ WT2){
  __shared__ float t[32][33];
  int b = blockIdx.x;
  const float* W; _Float16* WT; int R; int tb;
  if(b < 320){ W = W0; WT = WT0; R = 1280; tb = b; }
  else if(b < 960){ W = W1; WT = WT1; R = 2560; tb = b - 320; }
  else { W = W2; WT = WT2; R = 2560; tb = b - 960; }
  int tr = tb >> 3, tc = tb & 7;
  int tx = threadIdx.x & 31, ty = threadIdx.x >> 5;
#pragma unroll
  for(int i = 0; i < 4; i++){
    int r = tr * 32 + ty + 8 * i;
    t[ty + 8 * i][tx] = W[(size_t)r * 256 + tc * 32 + tx];
  }
  __syncthreads();
#pragma unroll
  for(int i = 0; i < 4; i++){
    int o = tc * 32 + ty + 8 * i;
    WT[(size_t)o * R + tr * 32 + tx] = (_Float16)t[tx][ty + 8 * i];
  }
}

// ---------------- MFMA GEMM (f16), XCD-pinned, single-sync double-buffer ----

__global__ __launch_bounds__(256) void k_gemm_f(const _Float16* __restrict__ A,
                                                const _Float16* __restrict__ BT,
                                                const float* __restrict__ bias,
                                                float* __restrict__ H,
                                                _Float16* __restrict__ tx2,
                                                int M, int Ktot){
  int b = blockIdx.x;
  int xcd = b & 7;
  int l = b >> 3;
  int m = xcd + 8 * (l >> 2);
  int n = l & 3;
  if(m * 64 >= M) return;
  int row0 = m * 64, col0 = n * 64;

  __shared__ short As[2][64 * 64];
  __shared__ short Bs[2][64 * 64];
  int tid = threadIdx.x;
  int lane = tid & 63;
  int wave = tid >> 6;
  int l15 = lane & 15;
  int quad = lane >> 4;
  int wm = (wave & 1) * 32;
  int wn = (wave >> 1) * 32;

  int e0 = tid, e1 = tid + 256;
  int r0 = e0 >> 3, g0 = e0 & 7;
  int r1 = e1 >> 3, g1 = e1 & 7;
  int gr0 = row0 + r0, gr1 = row0 + r1;
  int sa0 = r0 * 64 + ((g0 ^ (r0 & 7)) * 8);
  int sa1 = r1 * 64 + ((g1 ^ (r1 & 7)) * 8);

  f32x4 acc[2][2] = {};
  uint4 av0, av1, bv0, bv1;

  auto load = [&](int k0){
    av0 = (gr0 < M) ? *(const uint4*)(A + (size_t)gr0 * Ktot + k0 + g0 * 8)
                    : make_uint4(0u, 0u, 0u, 0u);
    av1 = (gr1 < M) ? *(const uint4*)(A + (size_t)gr1 * Ktot + k0 + g1 * 8)
                    : make_uint4(0u, 0u, 0u, 0u);
    bv0 = *(const uint4*)(BT + (size_t)(col0 + r0) * Ktot + k0 + g0 * 8);
    bv1 = *(const uint4*)(BT + (size_t)(col0 + r1) * Ktot + k0 + g1 * 8);
  };
  auto stor = [&](int buf){
    *(uint4*)(&As[buf][sa0]) = av0;
    *(uint4*)(&As[buf][sa1]) = av1;
    *(uint4*)(&Bs[buf][sa0]) = bv0;
    *(uint4*)(&Bs[buf][sa1]) = bv1;
  };

  load(0);
  stor(0);
  __syncthreads();
  int nk = Ktot >> 6;
  for(int it = 0; it < nk; it++){
    int cur = it & 1;
    if(it + 1 < nk) load((it + 1) << 6);   // in flight across MFMAs
#pragma unroll
    for(int kk = 0; kk < 64; kk += 32){
      int g = (kk >> 3) + quad;
      half8 a[2], bb[2];
#pragma unroll
      for(int mi = 0; mi < 2; mi++){
        int r = wm + mi * 16 + l15;
        a[mi] = *(const half8*)(&As[cur][r * 64 + ((g ^ (r & 7)) * 8)]);
      }
#pragma unroll
      for(int ni = 0; ni < 2; ni++){
        int nn = wn + ni * 16 + l15;
        bb[ni] = *(const half8*)(&Bs[cur][nn * 64 + ((g ^ (nn & 7)) * 8)]);
      }
#pragma unroll
      for(int mi = 0; mi < 2; mi++)
#pragma unroll
        for(int ni = 0; ni < 2; ni++)
          acc[mi][ni] = __builtin_amdgcn_mfma_f32_16x16x32_f16(a[mi], bb[ni], acc[mi][ni], 0, 0, 0);
    }
    if(it + 1 < nk){
      stor(cur ^ 1);
      __syncthreads();
    }
  }

  const int K256 = KCHEB * C_HID;
#pragma unroll
  for(int mi = 0; mi < 2; mi++){
#pragma unroll
    for(int ni = 0; ni < 2; ni++){
      int gcol = col0 + wn + ni * 16 + l15;
      float bv = bias[gcol];
#pragma unroll
      for(int r = 0; r < 4; r++){
        int grow = row0 + wm + mi * 16 + quad * 4 + r;
        if(grow < M){
          float v = fmaxf(acc[mi][ni][r] + bv, 0.f);
          if(tx2) tx2[(size_t)grow * K256 + gcol] = (_Float16)v;
          else    H[(size_t)grow * C_HID + gcol] = v;
        }
      }
    }
  }
}

// ---------------- pooling + head ----------------

__global__ __launch_bounds__(256) void k_pool2(const float* __restrict__ h,
                                               const int* __restrict__ batch,
                                               float* __restrict__ gsum){
  int c  = threadIdx.x;
  int n0 = blockIdx.x * POOL_CHUNK;
  int n1 = n0 + POOL_CHUNK;
  if(n1 > N_NODES) n1 = N_NODES;
  if(n0 >= n1) return;
  float acc = 0.f;
  int cur = batch[n0];
  for(int n = n0; n < n1; n++){
    int g = batch[n];
    if(g != cur){
      atomicAdd(&gsum[cur * C_HID + c], acc);
      acc = 0.f;
      cur = g;
    }
    acc += h[(size_t)n * C_HID + c];
  }
  atomicAdd(&gsum[cur * C_HID + c], acc);
}

__global__ __launch_bounds__(128) void k_final(const float* __restrict__ gsum,
                                               const int* __restrict__ gcnt,
                                               const float* __restrict__ Wout,
                                               const float* __restrict__ bout,
                                               float* __restrict__ out){
  int g = blockIdx.x;
  int o = threadIdx.x;
  float inv = 1.f / fmaxf((float)gcnt[g], 1.f);
  float acc = bout[o];
  for(int c = 0; c < C_HID; c++) acc += gsum[g * C_HID + c] * inv * Wout[c * C_OUTC + o];
  out[g * C_OUTC + o] = acc;
}

// ---------------- host ----------------

extern "C" void kernel_launch(void* const* d_in, const int* in_sizes, int n_in,
                              void* d_out, int out_size, void* d_ws, size_t ws_size,
                              hipStream_t stream){
  const float* x    = (const float*)d_in[0];
  const float* W0   = (const float*)d_in[1];
  const float* b0   = (const float*)d_in[2];
  const float* W1   = (const float*)d_in[3];
  const float* b1   = (const float*)d_in[4];
  const float* W2   = (const float*)d_in[5];
  const float* b2   = (const float*)d_in[6];
  const float* Wout = (const float*)d_in[7];
  const float* bout = (const float*)d_in[8];
  const int*   ei   = (const int*)d_in[9];
  const int*   batch= (const int*)d_in[10];
  const int* src = ei;
  const int* dst = ei + N_EDGES;
  float* out = (float*)d_out;

  char* p = (char*)d_ws;
  auto alloc = [&](size_t bytes)->char*{ char* r = p; p += align_up(bytes, 256); return r; };

  int*   deg    = (int*)  alloc(N_NODES * 4);
  int*   indeg  = (int*)  alloc(N_NODES * 4);
  int*   offs   = (int*)  alloc((N_NODES + 1) * 4);
  int*   cursor = (int*)  alloc(N_NODES * 4);
  float* dis    = (float*)alloc(N_NODES * 4);
  int*   csr_s  = (int*)  alloc(N_EDGES * 4);
  unsigned* csr_wp = (unsigned*)alloc(N_EDGES * 4);
  int*   gcnt   = (int*)  alloc(N_GRAPHS * 4);
  int*   gstart = (int*)  alloc((N_GRAPHS + 1) * 4);
  float* gsum   = (float*)alloc(N_GRAPHS * C_HID * 4);
  // barrier state: 3 x 1280 flags + 3 go words
  int*   barMem = (int*)  alloc((3 * 1280 + 3) * 4);
  int* flagsA = barMem;            int* goA = barMem + 3 * 1280 + 0;
  int* flagsB = barMem + 1280;     int* goB = barMem + 3 * 1280 + 1;
  int* flagsC = barMem + 2 * 1280; int* goC = barMem + 3 * 1280 + 2;

  const size_t txBytes = (size_t)N_NODES * (KCHEB * C_HID) * 2;  // 51.2 MB
  _Float16* txP = (_Float16*)alloc(txBytes);
  _Float16* txQ = (_Float16*)alloc(txBytes);
  _Float16* WT0 = (_Float16*)alloc((size_t)KCHEB * C_IN  * C_HID * 2);
  _Float16* WT1 = (_Float16*)alloc((size_t)KCHEB * C_HID * C_HID * 2);
  _Float16* WT2 = (_Float16*)alloc((size_t)KCHEB * C_HID * C_HID * 2);
  float* Hb = (float*)alloc((size_t)N_NODES * C_HID * 4);

  hipMemsetAsync(deg,   0, N_NODES * 4, stream);
  hipMemsetAsync(indeg, 0, N_NODES * 4, stream);
  hipMemsetAsync(gsum,  0, N_GRAPHS * C_HID * 4, stream);
  hipMemsetAsync(barMem, 0, (3 * 1280 + 3) * 4, stream);

  const int TB = 256;
  int egrid = (N_EDGES + TB - 1) / TB;
  int ngrid = (N_NODES + TB - 1) / TB;

  k_deg<<<egrid, TB, 0, stream>>>(src, dst, deg, indeg);
  k_dis<<<ngrid, TB, 0, stream>>>(deg, dis);
  k_scan<<<1, 1024, 0, stream>>>(indeg, offs, cursor);
  k_scatter<<<egrid, TB, 0, stream>>>(src, dst, dis, cursor, csr_s, csr_wp);
  k_gbounds<<<1, 128, 0, stream>>>(batch, gstart, gcnt);
  k_wt3t<<<1600, 256, 0, stream>>>(W0, WT0, W1, WT1, W2, WT2);

  const int K128 = KCHEB * C_IN;   // 1280
  const int K256 = KCHEB * C_HID;  // 2560
  const int GEMM_BLOCKS = 640;
  const int PROP_H_BLOCKS = 1256;  // 2 halves x 625 groups, XCD-interleaved
  const int PROP_1_BLOCKS = N_NODES / 8;  // 1250

  // ---- layer 1: 9 Cheb steps in ONE persistent kernel, then GEMM ----
  {
    int ng = N_NODES * (C_IN / 4);
    k_f2h<C_IN><<<(ng + TB - 1) / TB, TB, 0, stream>>>(x, txP, K128);
    k_prop128_all<<<PROP_1_BLOCKS, 256, 0, stream>>>(txP, csr_s, csr_wp, offs, flagsA, goA);
    k_gemm_f<<<GEMM_BLOCKS, 256, 0, stream>>>(txP, WT0, b0, nullptr, txQ, N_NODES, K128);
  }

  // ---- layer 2 ----
  {
    k_prop256_all<<<PROP_H_BLOCKS, 256, 0, stream>>>(txQ, csr_s, csr_wp, offs, flagsB, goB);
    k_gemm_f<<<GEMM_BLOCKS, 256, 0, stream>>>(txQ, WT1, b1, nullptr, txP, N_NODES, K256);
  }

  // ---- layer 3 ----
  {
    k_prop256_all<<<PROP_H_BLOCKS, 256, 0, stream>>>(txP, csr_s, csr_wp, offs, flagsC, goC);
    k_gemm_f<<<GEMM_BLOCKS, 256, 0, stream>>>(txP, WT2, b2, Hb, nullptr, N_NODES, K256);
  }

  k_pool2<<<(N_NODES + POOL_CHUNK - 1) / POOL_CHUNK, 256, 0, stream>>>(Hb, batch, gsum);
  k_final<<<N_GRAPHS, C_OUTC, 0, stream>>>(gsum, gcnt, Wout, bout, out);
}

// Round 4
// 722.054 us; speedup vs baseline: 6.2157x; 6.2157x over previous
//
#include <hip/hip_runtime.h>
#include <cstdint>
#include <cstddef>

#define N_NODES 10000
#define N_EDGES 320000
#define N_GRAPHS 64
#define KCHEB 10
#define C_IN 128
#define C_HID 256
#define C_OUTC 128
#define POOL_CHUNK 40

static inline size_t align_up(size_t v, size_t a){ return (v + a - 1) / a * a; }

typedef __attribute__((ext_vector_type(8))) _Float16 half8;
typedef __attribute__((ext_vector_type(2))) _Float16 h2;
typedef __attribute__((ext_vector_type(4))) float f32x4;

// ---------------- graph setup kernels ----------------

__global__ void k_deg(const int* __restrict__ src, const int* __restrict__ dst,
                      int* __restrict__ deg, int* __restrict__ indeg){
  int e = blockIdx.x*blockDim.x + threadIdx.x;
  if(e < N_EDGES){
    atomicAdd(&deg[src[e]], 1);
    atomicAdd(&indeg[dst[e]], 1);
  }
}

// scan over indeg -> offs/cursor; also computes dis = rsqrt(deg) (folded k_dis)
__global__ __launch_bounds__(1024) void k_scan(const int* __restrict__ cnt,
                                               int* __restrict__ offs,
                                               int* __restrict__ cursor,
                                               const int* __restrict__ deg,
                                               float* __restrict__ dis){
  __shared__ int part[1024];
  const int n = N_NODES;
  const int CH = (n + 1023) / 1024;
  int tid = threadIdx.x;
  int base = tid * CH;
  int s = 0;
  for(int i = 0; i < CH; i++){
    int idx = base + i;
    if(idx < n){
      s += cnt[idx];
      int d = deg[idx];
      dis[idx] = d > 0 ? rsqrtf((float)d) : 0.f;
    }
  }
  part[tid] = s;
  __syncthreads();
  for(int off = 1; off < 1024; off <<= 1){
    int v = (tid >= off) ? part[tid - off] : 0;
    __syncthreads();
    part[tid] += v;
    __syncthreads();
  }
  int run = (tid == 0) ? 0 : part[tid - 1];
  for(int i = 0; i < CH; i++){
    int idx = base + i;
    if(idx < n){
      offs[idx] = run;
      cursor[idx] = run;
      run += cnt[idx];
    }
  }
  if(tid == 1023) offs[n] = part[1023];
}

// scatter + edge-weight in one pass; weight stored as duplicated f16 pair
// (converted ONCE here instead of per edge per prop step).
__global__ void k_scatter(const int* __restrict__ src, const int* __restrict__ dst,
                          const float* __restrict__ dis, int* __restrict__ cursor,
                          int* __restrict__ csr_s, unsigned* __restrict__ csr_wp){
  int e = blockIdx.x*blockDim.x + threadIdx.x;
  if(e < N_EDGES){
    int s = src[e], d = dst[e];
    float w = -dis[s] * dis[d];
    unsigned short wb = __builtin_bit_cast(unsigned short, (_Float16)w);
    int p = atomicAdd(&cursor[d], 1);
    csr_s[p] = s;
    csr_wp[p] = (unsigned)wb * 0x00010001u;
  }
}

__global__ __launch_bounds__(128) void k_gbounds(const int* __restrict__ batch,
                                                 int* __restrict__ gstart,
                                                 int* __restrict__ gcnt){
  int g = threadIdx.x;
  if(g <= N_GRAPHS){
    int lo = 0, hi = N_NODES;
    while(lo < hi){
      int mid = (lo + hi) >> 1;
      if(batch[mid] < g) lo = mid + 1; else hi = mid;
    }
    gstart[g] = lo;
  }
  __syncthreads();
  if(g < N_GRAPHS) gcnt[g] = gstart[g + 1] - gstart[g];
}

// ---------------- propagation (f16 state, v_pk_fma_f16) ----------------

__device__ inline void hfma4(h2* a, uint4 v, unsigned wbits){
  h2 w2 = __builtin_bit_cast(h2, wbits);
  a[0] += __builtin_bit_cast(h2, v.x) * w2;
  a[1] += __builtin_bit_cast(h2, v.y) * w2;
  a[2] += __builtin_bit_cast(h2, v.z) * w2;
  a[3] += __builtin_bit_cast(h2, v.w) * w2;
}

// 256-ch propagation, channel-split into two 128-ch halves pinned to XCD
// groups (bid%8 -> XCD; 0-3 = half0, 4-7 = half1). Per-XCD gather working
// set 2.56 MB < 4 MB L2. 16-lane groups own one node-half.
__global__ __launch_bounds__(256) void k_prop256h(const _Float16* __restrict__ Xb,
                                                  const _Float16* __restrict__ Pb,
                                                  _Float16* __restrict__ tx,
                                                  const int* __restrict__ csr_s,
                                                  const unsigned* __restrict__ csr_wp,
                                                  const int* __restrict__ offs,
                                                  float alpha){
  const int stride  = KCHEB * C_HID;
  const int strideB = stride * 2;        // 5120 bytes
  int bid  = blockIdx.x;
  int half = (bid >> 2) & 1;
  int lh   = (bid >> 3) * 4 + (bid & 3);
  int l15  = threadIdx.x & 15;
  int lane = threadIdx.x & 63;
  int b16  = lane & 48;
  int e8   = l15 & 7;
  int node = lh * 16 + (threadIdx.x >> 4);
  if(node >= N_NODES) return;
  int j0 = offs[node], j1 = offs[node + 1];
  h2 a[4] = {};
  const char* __restrict__ gbase = (const char*)Xb + (half * (C_HID/2) + l15 * 8) * 2;
  int j = j0;
  int sv = 0; unsigned wv = 0;
  bool have = (j + 7 < j1);
  if(have){ sv = csr_s[j + e8] * strideB; wv = csr_wp[j + e8]; }
  while(have){
    int jn = j + 8;
    bool more = (jn + 7 < j1);
    int sv2 = 0; unsigned wv2 = 0;
    if(more){ sv2 = csr_s[jn + e8] * strideB; wv2 = csr_wp[jn + e8]; }
    uint4 v[8];
#pragma unroll
    for(int i = 0; i < 8; i++){
      int si = __shfl(sv, b16 + i);
      v[i] = *(const uint4*)(gbase + si);
    }
#pragma unroll
    for(int i = 0; i < 8; i++){
      unsigned wi = (unsigned)__shfl((int)wv, b16 + i);
      hfma4(a, v[i], wi);
    }
    sv = sv2; wv = wv2; j = jn; have = more;
  }
  for(; j < j1; j++){
    int si = csr_s[j] * strideB;
    uint4 v0 = *(const uint4*)(gbase + si);
    hfma4(a, v0, csr_wp[j]);
  }
  _Float16 ah = (_Float16)alpha;
  h2 al = {ah, ah};
  h2 r[4];
#pragma unroll
  for(int i = 0; i < 4; i++) r[i] = a[i] * al;
  size_t off = (size_t)node * stride + half * (C_HID/2) + l15 * 8;
  if(Pb){
    uint4 pv = *(const uint4*)(Pb + off);
    r[0] -= __builtin_bit_cast(h2, pv.x);
    r[1] -= __builtin_bit_cast(h2, pv.y);
    r[2] -= __builtin_bit_cast(h2, pv.z);
    r[3] -= __builtin_bit_cast(h2, pv.w);
  }
  uint4 ob;
  ob.x = __builtin_bit_cast(unsigned, r[0]);
  ob.y = __builtin_bit_cast(unsigned, r[1]);
  ob.z = __builtin_bit_cast(unsigned, r[2]);
  ob.w = __builtin_bit_cast(unsigned, r[3]);
  *(uint4*)(tx + off) = ob;
}

__global__ __launch_bounds__(256) void k_prop128(const _Float16* __restrict__ Xb,
                                                 const _Float16* __restrict__ Pb,
                                                 _Float16* __restrict__ tx,
                                                 const int* __restrict__ csr_s,
                                                 const unsigned* __restrict__ csr_wp,
                                                 const int* __restrict__ offs,
                                                 float alpha){
  const int stride  = KCHEB * C_IN;      // 1280 elements
  const int strideB = stride * 2;        // 2560 bytes
  int hl   = threadIdx.x & 31;
  int b32  = threadIdx.x & 32;
  int e8   = hl & 7;
  int node = blockIdx.x * 8 + (threadIdx.x >> 5);
  int j0 = offs[node], j1 = offs[node + 1];
  h2 a[2] = {};
  const char* __restrict__ gbase = (const char*)Xb + hl * 8;
  int j = j0;
  int sv = 0; unsigned wv = 0;
  bool have = (j + 7 < j1);
  if(have){ sv = csr_s[j + e8] * strideB; wv = csr_wp[j + e8]; }
  while(have){
    int jn = j + 8;
    bool more = (jn + 7 < j1);
    int sv2 = 0; unsigned wv2 = 0;
    if(more){ sv2 = csr_s[jn + e8] * strideB; wv2 = csr_wp[jn + e8]; }
    uint2 v[8];
#pragma unroll
    for(int i = 0; i < 8; i++){
      int si = __shfl(sv, b32 + i);
      v[i] = *(const uint2*)(gbase + si);
    }
#pragma unroll
    for(int i = 0; i < 8; i++){
      unsigned wi = (unsigned)__shfl((int)wv, b32 + i);
      h2 w2 = __builtin_bit_cast(h2, wi);
      a[0] += __builtin_bit_cast(h2, v[i].x) * w2;
      a[1] += __builtin_bit_cast(h2, v[i].y) * w2;
    }
    sv = sv2; wv = wv2; j = jn; have = more;
  }
  for(; j < j1; j++){
    int si = csr_s[j] * strideB;
    h2 w2 = __builtin_bit_cast(h2, csr_wp[j]);
    uint2 v0 = *(const uint2*)(gbase + si);
    a[0] += __builtin_bit_cast(h2, v0.x) * w2;
    a[1] += __builtin_bit_cast(h2, v0.y) * w2;
  }
  _Float16 ah = (_Float16)alpha;
  h2 al = {ah, ah};
  h2 r0 = a[0] * al, r1 = a[1] * al;
  size_t off = (size_t)node * stride + hl * 4;
  if(Pb){
    uint2 pv = *(const uint2*)(Pb + off);
    r0 -= __builtin_bit_cast(h2, pv.x);
    r1 -= __builtin_bit_cast(h2, pv.y);
  }
  uint2 ob;
  ob.x = __builtin_bit_cast(unsigned, r0);
  ob.y = __builtin_bit_cast(unsigned, r1);
  *(uint2*)(tx + off) = ob;
}

// fp32 [rows][C] -> f16 strided slot (layer-1 input only)
template<int C>
__global__ void k_f2h(const float* __restrict__ X, _Float16* __restrict__ tx,
                      int tx_stride){
  int idx = blockIdx.x * blockDim.x + threadIdx.x;
  const int GPR = C / 4;
  if(idx < N_NODES * GPR){
    int r = idx / GPR;
    int c = (idx - r * GPR) * 4;
    float4 v = *(const float4*)(X + (size_t)r * C + c);
    h2 p0 = {(_Float16)v.x, (_Float16)v.y};
    h2 p1 = {(_Float16)v.z, (_Float16)v.w};
    uint2 ob;
    ob.x = __builtin_bit_cast(unsigned, p0);
    ob.y = __builtin_bit_cast(unsigned, p1);
    *(uint2*)(tx + (size_t)r * tx_stride + c) = ob;
  }
}

// LDS-tiled weight transpose: WT[o][kc] = (f16)W[kc][o], W is [R][256].
__global__ __launch_bounds__(256) void k_wt3t(const float* __restrict__ W0, _Float16* __restrict__ WT0,
                                              const float* __restrict__ W1, _Float16* __restrict__ WT1,
                                              const float* __restrict__ W2, _Float16* __restrict__ WT2){
  __shared__ float t[32][33];
  int b = blockIdx.x;
  const float* W; _Float16* WT; int R; int tb;
  if(b < 320){ W = W0; WT = WT0; R = 1280; tb = b; }
  else if(b < 960){ W = W1; WT = WT1; R = 2560; tb = b - 320; }
  else { W = W2; WT = WT2; R = 2560; tb = b - 960; }
  int tr = tb >> 3, tc = tb & 7;
  int tx = threadIdx.x & 31, ty = threadIdx.x >> 5;
#pragma unroll
  for(int i = 0; i < 4; i++){
    int r = tr * 32 + ty + 8 * i;
    t[ty + 8 * i][tx] = W[(size_t)r * 256 + tc * 32 + tx];
  }
  __syncthreads();
#pragma unroll
  for(int i = 0; i < 4; i++){
    int o = tc * 32 + ty + 8 * i;
    WT[(size_t)o * R + tr * 32 + tx] = (_Float16)t[tx][ty + 8 * i];
  }
}

// ---------------- MFMA GEMM (f16), BM=128 BN=64, 4 waves x (64x32) --------
// Per wave per K-64: 16 MFMAs, 12 ds_read_b128 (0.75 reads/MFMA vs 1.0 in the
// old 64x64 shape) — the old shape was LDS-BW-bound. XCD-pinned, single-sync
// double-buffer. If tx2 != null: write relu(A@B+bias) f16 to tx2 (stride
// K256); else fp32 to H (stride C_HID).

__global__ __launch_bounds__(256) void k_gemm_f(const _Float16* __restrict__ A,
                                                const _Float16* __restrict__ BT,
                                                const float* __restrict__ bias,
                                                float* __restrict__ H,
                                                _Float16* __restrict__ tx2,
                                                int M, int Ktot){
  int b = blockIdx.x;
  int xcd = b & 7;
  int l = b >> 3;
  int m = xcd + 8 * (l >> 2);   // 0..79 row-tile (128 rows)
  int n = l & 3;                // 0..3 col-tile (64 cols)
  if(m * 128 >= M) return;
  int row0 = m * 128, col0 = n * 64;

  __shared__ short As[2][128 * 64];
  __shared__ short Bs[2][64 * 64];
  int tid = threadIdx.x;
  int lane = tid & 63;
  int wave = tid >> 6;
  int l15 = lane & 15;
  int quad = lane >> 4;
  int wm = (wave & 1) * 64;
  int wn = (wave >> 1) * 32;

  // staging map: A has 1024 (r,g) cells (r<128, g<8), B has 512 (r<64, g<8)
  int ar[4], ag[4], asw[4], agr[4];
#pragma unroll
  for(int i = 0; i < 4; i++){
    int e = tid + 256 * i;
    ar[i] = e >> 3; ag[i] = e & 7;
    agr[i] = row0 + ar[i];
    asw[i] = ar[i] * 64 + ((ag[i] ^ (ar[i] & 7)) * 8);
  }
  int br[2], bg[2], bsw[2];
#pragma unroll
  for(int i = 0; i < 2; i++){
    int e = tid + 256 * i;
    br[i] = e >> 3; bg[i] = e & 7;
    bsw[i] = br[i] * 64 + ((bg[i] ^ (br[i] & 7)) * 8);
  }

  f32x4 acc[4][2] = {};
  uint4 av[4], bv[2];

  auto load = [&](int k0){
#pragma unroll
    for(int i = 0; i < 4; i++)
      av[i] = (agr[i] < M) ? *(const uint4*)(A + (size_t)agr[i] * Ktot + k0 + ag[i] * 8)
                           : make_uint4(0u, 0u, 0u, 0u);
#pragma unroll
    for(int i = 0; i < 2; i++)
      bv[i] = *(const uint4*)(BT + (size_t)(col0 + br[i]) * Ktot + k0 + bg[i] * 8);
  };
  auto stor = [&](int buf){
#pragma unroll
    for(int i = 0; i < 4; i++) *(uint4*)(&As[buf][asw[i]]) = av[i];
#pragma unroll
    for(int i = 0; i < 2; i++) *(uint4*)(&Bs[buf][bsw[i]]) = bv[i];
  };

  load(0);
  stor(0);
  __syncthreads();
  int nk = Ktot >> 6;
  for(int it = 0; it < nk; it++){
    int cur = it & 1;
    if(it + 1 < nk) load((it + 1) << 6);   // in flight across MFMAs
#pragma unroll
    for(int kk = 0; kk < 64; kk += 32){
      int g = (kk >> 3) + quad;
      half8 a[4], bb[2];
#pragma unroll
      for(int mi = 0; mi < 4; mi++){
        int r = wm + mi * 16 + l15;
        a[mi] = *(const half8*)(&As[cur][r * 64 + ((g ^ (r & 7)) * 8)]);
      }
#pragma unroll
      for(int ni = 0; ni < 2; ni++){
        int nn = wn + ni * 16 + l15;
        bb[ni] = *(const half8*)(&Bs[cur][nn * 64 + ((g ^ (nn & 7)) * 8)]);
      }
#pragma unroll
      for(int mi = 0; mi < 4; mi++)
#pragma unroll
        for(int ni = 0; ni < 2; ni++)
          acc[mi][ni] = __builtin_amdgcn_mfma_f32_16x16x32_f16(a[mi], bb[ni], acc[mi][ni], 0, 0, 0);
    }
    if(it + 1 < nk){
      // buf[cur^1]'s last readers finished before the barrier that opened this
      // iteration — safe to overwrite with only ONE barrier per iteration.
      stor(cur ^ 1);
      __syncthreads();
    }
  }

  const int K256 = KCHEB * C_HID;
#pragma unroll
  for(int mi = 0; mi < 4; mi++){
#pragma unroll
    for(int ni = 0; ni < 2; ni++){
      int gcol = col0 + wn + ni * 16 + l15;
      float bvv = bias[gcol];
#pragma unroll
      for(int r = 0; r < 4; r++){
        int grow = row0 + wm + mi * 16 + quad * 4 + r;
        if(grow < M){
          float v = fmaxf(acc[mi][ni][r] + bvv, 0.f);
          if(tx2) tx2[(size_t)grow * K256 + gcol] = (_Float16)v;
          else    H[(size_t)grow * C_HID + gcol] = v;
        }
      }
    }
  }
}

// ---------------- pooling + head ----------------

__global__ __launch_bounds__(256) void k_pool2(const float* __restrict__ h,
                                               const int* __restrict__ batch,
                                               float* __restrict__ gsum){
  int c  = threadIdx.x;
  int n0 = blockIdx.x * POOL_CHUNK;
  int n1 = n0 + POOL_CHUNK;
  if(n1 > N_NODES) n1 = N_NODES;
  if(n0 >= n1) return;
  float acc = 0.f;
  int cur = batch[n0];
  for(int n = n0; n < n1; n++){
    int g = batch[n];
    if(g != cur){
      atomicAdd(&gsum[cur * C_HID + c], acc);
      acc = 0.f;
      cur = g;
    }
    acc += h[(size_t)n * C_HID + c];
  }
  atomicAdd(&gsum[cur * C_HID + c], acc);
}

__global__ __launch_bounds__(128) void k_final(const float* __restrict__ gsum,
                                               const int* __restrict__ gcnt,
                                               const float* __restrict__ Wout,
                                               const float* __restrict__ bout,
                                               float* __restrict__ out){
  int g = blockIdx.x;
  int o = threadIdx.x;
  float inv = 1.f / fmaxf((float)gcnt[g], 1.f);
  float acc = bout[o];
  for(int c = 0; c < C_HID; c++) acc += gsum[g * C_HID + c] * inv * Wout[c * C_OUTC + o];
  out[g * C_OUTC + o] = acc;
}

// ---------------- host ----------------

extern "C" void kernel_launch(void* const* d_in, const int* in_sizes, int n_in,
                              void* d_out, int out_size, void* d_ws, size_t ws_size,
                              hipStream_t stream){
  const float* x    = (const float*)d_in[0];
  const float* W0   = (const float*)d_in[1];
  const float* b0   = (const float*)d_in[2];
  const float* W1   = (const float*)d_in[3];
  const float* b1   = (const float*)d_in[4];
  const float* W2   = (const float*)d_in[5];
  const float* b2   = (const float*)d_in[6];
  const float* Wout = (const float*)d_in[7];
  const float* bout = (const float*)d_in[8];
  const int*   ei   = (const int*)d_in[9];
  const int*   batch= (const int*)d_in[10];
  const int* src = ei;
  const int* dst = ei + N_EDGES;
  float* out = (float*)d_out;

  char* p = (char*)d_ws;
  auto alloc = [&](size_t bytes)->char*{ char* r = p; p += align_up(bytes, 256); return r; };

  int*   deg    = (int*)  alloc(N_NODES * 4);
  int*   indeg  = (int*)  alloc(N_NODES * 4);
  int*   offs   = (int*)  alloc((N_NODES + 1) * 4);
  int*   cursor = (int*)  alloc(N_NODES * 4);
  float* dis    = (float*)alloc(N_NODES * 4);
  int*   csr_s  = (int*)  alloc(N_EDGES * 4);
  unsigned* csr_wp = (unsigned*)alloc(N_EDGES * 4);
  int*   gcnt   = (int*)  alloc(N_GRAPHS * 4);
  int*   gstart = (int*)  alloc((N_GRAPHS + 1) * 4);
  float* gsum   = (float*)alloc(N_GRAPHS * C_HID * 4);

  const size_t txBytes = (size_t)N_NODES * (KCHEB * C_HID) * 2;  // 51.2 MB
  _Float16* txP = (_Float16*)alloc(txBytes);
  _Float16* txQ = (_Float16*)alloc(txBytes);
  _Float16* WT0 = (_Float16*)alloc((size_t)KCHEB * C_IN  * C_HID * 2);
  _Float16* WT1 = (_Float16*)alloc((size_t)KCHEB * C_HID * C_HID * 2);
  _Float16* WT2 = (_Float16*)alloc((size_t)KCHEB * C_HID * C_HID * 2);
  float* Hb = (float*)alloc((size_t)N_NODES * C_HID * 4);

  hipMemsetAsync(deg,   0, N_NODES * 4, stream);
  hipMemsetAsync(indeg, 0, N_NODES * 4, stream);
  hipMemsetAsync(gsum,  0, N_GRAPHS * C_HID * 4, stream);

  const int TB = 256;
  int egrid = (N_EDGES + TB - 1) / TB;

  k_deg<<<egrid, TB, 0, stream>>>(src, dst, deg, indeg);
  k_scan<<<1, 1024, 0, stream>>>(indeg, offs, cursor, deg, dis);
  k_scatter<<<egrid, TB, 0, stream>>>(src, dst, dis, cursor, csr_s, csr_wp);
  k_gbounds<<<1, 128, 0, stream>>>(batch, gstart, gcnt);
  k_wt3t<<<1600, 256, 0, stream>>>(W0, WT0, W1, WT1, W2, WT2);

  const int K128 = KCHEB * C_IN;   // 1280
  const int K256 = KCHEB * C_HID;  // 2560
  const int GEMM_BLOCKS = 320;     // 8 xcd * 10 row-groups * 4 col-tiles
  const int PROP_H_BLOCKS = 1256;  // 2 halves x 625 groups, XCD-interleaved
  const int PROP_1_BLOCKS = N_NODES / 8;  // 1250

  // ---- layer 1 (Cin=128, A in txP with stride K128) ----
  {
    int ng = N_NODES * (C_IN / 4);
    k_f2h<C_IN><<<(ng + TB - 1) / TB, TB, 0, stream>>>(x, txP, K128);
    for(int k = 1; k < KCHEB; k++){
      const _Float16* Xb = txP + (size_t)(k - 1) * C_IN;
      const _Float16* Pb = (k >= 2) ? txP + (size_t)(k - 2) * C_IN : nullptr;
      _Float16* tx = txP + (size_t)k * C_IN;
      k_prop128<<<PROP_1_BLOCKS, 256, 0, stream>>>(Xb, Pb, tx, csr_s, csr_wp, offs,
                                                   k == 1 ? 1.f : 2.f);
    }
    k_gemm_f<<<GEMM_BLOCKS, 256, 0, stream>>>(txP, WT0, b0, nullptr, txQ, N_NODES, K128);
  }

  // ---- layer 2 (A in txQ, stride K256) -> f16 slot 0 of txP ----
  {
    for(int k = 1; k < KCHEB; k++){
      const _Float16* Xb = txQ + (size_t)(k - 1) * C_HID;
      const _Float16* Pb = (k >= 2) ? txQ + (size_t)(k - 2) * C_HID : nullptr;
      _Float16* tx = txQ + (size_t)k * C_HID;
      k_prop256h<<<PROP_H_BLOCKS, 256, 0, stream>>>(Xb, Pb, tx, csr_s, csr_wp, offs,
                                                    k == 1 ? 1.f : 2.f);
    }
    k_gemm_f<<<GEMM_BLOCKS, 256, 0, stream>>>(txQ, WT1, b1, nullptr, txP, N_NODES, K256);
  }

  // ---- layer 3 (A in txP, stride K256) -> fp32 Hb ----
  {
    for(int k = 1; k < KCHEB; k++){
      const _Float16* Xb = txP + (size_t)(k - 1) * C_HID;
      const _Float16* Pb = (k >= 2) ? txP + (size_t)(k - 2) * C_HID : nullptr;
      _Float16* tx = txP + (size_t)k * C_HID;
      k_prop256h<<<PROP_H_BLOCKS, 256, 0, stream>>>(Xb, Pb, tx, csr_s, csr_wp, offs,
                                                    k == 1 ? 1.f : 2.f);
    }
    k_gemm_f<<<GEMM_BLOCKS, 256, 0, stream>>>(txP, WT2, b2, Hb, nullptr, N_NODES, K256);
  }

  k_pool2<<<(N_NODES + POOL_CHUNK - 1) / POOL_CHUNK, 256, 0, stream>>>(Hb, batch, gsum);
  k_final<<<N_GRAPHS, C_OUTC, 0, stream>>>(gsum, gcnt, Wout, bout, out);
}

// Round 5
// 626.845 us; speedup vs baseline: 7.1598x; 1.1519x over previous
//
#include <hip/hip_runtime.h>
#include <cstdint>
#include <cstddef>

#define N_NODES 10000
#define N_EDGES 320000
#define N_GRAPHS 64
#define KCHEB 10
#define C_IN 128
#define C_HID 256
#define C_OUTC 128
#define POOL_CHUNK 40

static inline size_t align_up(size_t v, size_t a){ return (v + a - 1) / a * a; }

typedef __attribute__((ext_vector_type(8))) _Float16 half8;
typedef __attribute__((ext_vector_type(2))) _Float16 h2;
typedef __attribute__((ext_vector_type(4))) float f32x4;

// ---------------- graph setup kernels ----------------

__global__ void k_deg(const int* __restrict__ src, const int* __restrict__ dst,
                      int* __restrict__ deg, int* __restrict__ indeg){
  int e = blockIdx.x*blockDim.x + threadIdx.x;
  if(e < N_EDGES){
    atomicAdd(&deg[src[e]], 1);
    atomicAdd(&indeg[dst[e]], 1);
  }
}

// Single-block mega-kernel: scan(indeg)->offs/cursor, dis=rsqrt(deg), and a
// counting sort of nodes by in-degree (DESCENDING) -> perm. perm makes
// co-waved node-groups equal-degree (kills max-of-N divergence in props) and
// launches big blocks first. Per-node arithmetic unchanged -> identical output.
__global__ __launch_bounds__(1024) void k_scan(const int* __restrict__ cnt,
                                               int* __restrict__ offs,
                                               int* __restrict__ cursor,
                                               const int* __restrict__ deg,
                                               float* __restrict__ dis,
                                               int* __restrict__ perm){
  __shared__ int part[1024];
  __shared__ int hist[256];
  __shared__ int hoff[256];
  const int n = N_NODES;
  const int CH = (n + 1023) / 1024;
  int tid = threadIdx.x;
  int base = tid * CH;
  if(tid < 256) hist[tid] = 0;
  int s = 0;
  for(int i = 0; i < CH; i++){
    int idx = base + i;
    if(idx < n){
      s += cnt[idx];
      int d = deg[idx];
      dis[idx] = d > 0 ? rsqrtf((float)d) : 0.f;
    }
  }
  part[tid] = s;
  __syncthreads();
  for(int off = 1; off < 1024; off <<= 1){
    int v = (tid >= off) ? part[tid - off] : 0;
    __syncthreads();
    part[tid] += v;
    __syncthreads();
  }
  int run = (tid == 0) ? 0 : part[tid - 1];
  for(int i = 0; i < CH; i++){
    int idx = base + i;
    if(idx < n){
      offs[idx] = run;
      cursor[idx] = run;
      run += cnt[idx];
      int d = cnt[idx]; if(d > 255) d = 255;
      atomicAdd(&hist[d], 1);
    }
  }
  if(tid == 1023) offs[n] = part[1023];
  __syncthreads();
  if(tid == 0){
    int r2 = 0;
    for(int d = 255; d >= 0; d--){ hoff[d] = r2; r2 += hist[d]; }
  }
  __syncthreads();
  for(int i = 0; i < CH; i++){
    int idx = base + i;
    if(idx < n){
      int d = cnt[idx]; if(d > 255) d = 255;
      int p0 = atomicAdd(&hoff[d], 1);
      perm[p0] = idx;
    }
  }
}

// scatter + edge-weight in one pass; weight stored as duplicated f16 pair
__global__ void k_scatter(const int* __restrict__ src, const int* __restrict__ dst,
                          const float* __restrict__ dis, int* __restrict__ cursor,
                          int* __restrict__ csr_s, unsigned* __restrict__ csr_wp){
  int e = blockIdx.x*blockDim.x + threadIdx.x;
  if(e < N_EDGES){
    int s = src[e], d = dst[e];
    float w = -dis[s] * dis[d];
    unsigned short wb = __builtin_bit_cast(unsigned short, (_Float16)w);
    int p = atomicAdd(&cursor[d], 1);
    csr_s[p] = s;
    csr_wp[p] = (unsigned)wb * 0x00010001u;
  }
}

__global__ __launch_bounds__(128) void k_gbounds(const int* __restrict__ batch,
                                                 int* __restrict__ gstart,
                                                 int* __restrict__ gcnt){
  int g = threadIdx.x;
  if(g <= N_GRAPHS){
    int lo = 0, hi = N_NODES;
    while(lo < hi){
      int mid = (lo + hi) >> 1;
      if(batch[mid] < g) lo = mid + 1; else hi = mid;
    }
    gstart[g] = lo;
  }
  __syncthreads();
  if(g < N_GRAPHS) gcnt[g] = gstart[g + 1] - gstart[g];
}

// ---------------- propagation (f16 state, v_pk_fma_f16, degree-sorted) -----

__device__ inline void hfma4(h2* a, uint4 v, unsigned wbits){
  h2 w2 = __builtin_bit_cast(h2, wbits);
  a[0] += __builtin_bit_cast(h2, v.x) * w2;
  a[1] += __builtin_bit_cast(h2, v.y) * w2;
  a[2] += __builtin_bit_cast(h2, v.z) * w2;
  a[3] += __builtin_bit_cast(h2, v.w) * w2;
}

// 256-ch propagation, channel-split halves pinned to XCD groups (bid%8 ->
// XCD; 0-3 = half0, 4-7 = half1): per-XCD gather working set 2.56 MB < 4 MB
// L2. 16-lane groups own one node-half; nodes assigned via degree-sorted perm.
__global__ __launch_bounds__(256) void k_prop256h(const _Float16* __restrict__ Xb,
                                                  const _Float16* __restrict__ Pb,
                                                  _Float16* __restrict__ tx,
                                                  const int* __restrict__ csr_s,
                                                  const unsigned* __restrict__ csr_wp,
                                                  const int* __restrict__ offs,
                                                  const int* __restrict__ perm,
                                                  float alpha){
  const int stride  = KCHEB * C_HID;
  const int strideB = stride * 2;        // 5120 bytes
  int bid  = blockIdx.x;
  int half = (bid >> 2) & 1;
  int lh   = (bid >> 3) * 4 + (bid & 3);
  int l15  = threadIdx.x & 15;
  int lane = threadIdx.x & 63;
  int b16  = lane & 48;
  int e8   = l15 & 7;
  int nidx = lh * 16 + (threadIdx.x >> 4);
  if(nidx >= N_NODES) return;
  int node = perm[nidx];
  int j0 = offs[node], j1 = offs[node + 1];
  h2 a[4] = {};
  const char* __restrict__ gbase = (const char*)Xb + (half * (C_HID/2) + l15 * 8) * 2;
  int j = j0;
  int sv = 0; unsigned wv = 0;
  bool have = (j + 7 < j1);
  if(have){ sv = csr_s[j + e8] * strideB; wv = csr_wp[j + e8]; }
  while(have){
    int jn = j + 8;
    bool more = (jn + 7 < j1);
    int sv2 = 0; unsigned wv2 = 0;
    if(more){ sv2 = csr_s[jn + e8] * strideB; wv2 = csr_wp[jn + e8]; }
    uint4 v[8];
#pragma unroll
    for(int i = 0; i < 8; i++){
      int si = __shfl(sv, b16 + i);
      v[i] = *(const uint4*)(gbase + si);
    }
#pragma unroll
    for(int i = 0; i < 8; i++){
      unsigned wi = (unsigned)__shfl((int)wv, b16 + i);
      hfma4(a, v[i], wi);
    }
    sv = sv2; wv = wv2; j = jn; have = more;
  }
  for(; j < j1; j++){
    int si = csr_s[j] * strideB;
    uint4 v0 = *(const uint4*)(gbase + si);
    hfma4(a, v0, csr_wp[j]);
  }
  _Float16 ah = (_Float16)alpha;
  h2 al = {ah, ah};
  h2 r[4];
#pragma unroll
  for(int i = 0; i < 4; i++) r[i] = a[i] * al;
  size_t off = (size_t)node * stride + half * (C_HID/2) + l15 * 8;
  if(Pb){
    uint4 pv = *(const uint4*)(Pb + off);
    r[0] -= __builtin_bit_cast(h2, pv.x);
    r[1] -= __builtin_bit_cast(h2, pv.y);
    r[2] -= __builtin_bit_cast(h2, pv.z);
    r[3] -= __builtin_bit_cast(h2, pv.w);
  }
  uint4 ob;
  ob.x = __builtin_bit_cast(unsigned, r[0]);
  ob.y = __builtin_bit_cast(unsigned, r[1]);
  ob.z = __builtin_bit_cast(unsigned, r[2]);
  ob.w = __builtin_bit_cast(unsigned, r[3]);
  *(uint4*)(tx + off) = ob;
}

__global__ __launch_bounds__(256) void k_prop128(const _Float16* __restrict__ Xb,
                                                 const _Float16* __restrict__ Pb,
                                                 _Float16* __restrict__ tx,
                                                 const int* __restrict__ csr_s,
                                                 const unsigned* __restrict__ csr_wp,
                                                 const int* __restrict__ offs,
                                                 const int* __restrict__ perm,
                                                 float alpha){
  const int stride  = KCHEB * C_IN;      // 1280 elements
  const int strideB = stride * 2;        // 2560 bytes
  int hl   = threadIdx.x & 31;
  int b32  = threadIdx.x & 32;
  int e8   = hl & 7;
  int node = perm[blockIdx.x * 8 + (threadIdx.x >> 5)];
  int j0 = offs[node], j1 = offs[node + 1];
  h2 a[2] = {};
  const char* __restrict__ gbase = (const char*)Xb + hl * 8;
  int j = j0;
  int sv = 0; unsigned wv = 0;
  bool have = (j + 7 < j1);
  if(have){ sv = csr_s[j + e8] * strideB; wv = csr_wp[j + e8]; }
  while(have){
    int jn = j + 8;
    bool more = (jn + 7 < j1);
    int sv2 = 0; unsigned wv2 = 0;
    if(more){ sv2 = csr_s[jn + e8] * strideB; wv2 = csr_wp[jn + e8]; }
    uint2 v[8];
#pragma unroll
    for(int i = 0; i < 8; i++){
      int si = __shfl(sv, b32 + i);
      v[i] = *(const uint2*)(gbase + si);
    }
#pragma unroll
    for(int i = 0; i < 8; i++){
      unsigned wi = (unsigned)__shfl((int)wv, b32 + i);
      h2 w2 = __builtin_bit_cast(h2, wi);
      a[0] += __builtin_bit_cast(h2, v[i].x) * w2;
      a[1] += __builtin_bit_cast(h2, v[i].y) * w2;
    }
    sv = sv2; wv = wv2; j = jn; have = more;
  }
  for(; j < j1; j++){
    int si = csr_s[j] * strideB;
    h2 w2 = __builtin_bit_cast(h2, csr_wp[j]);
    uint2 v0 = *(const uint2*)(gbase + si);
    a[0] += __builtin_bit_cast(h2, v0.x) * w2;
    a[1] += __builtin_bit_cast(h2, v0.y) * w2;
  }
  _Float16 ah = (_Float16)alpha;
  h2 al = {ah, ah};
  h2 r0 = a[0] * al, r1 = a[1] * al;
  size_t off = (size_t)node * stride + hl * 4;
  if(Pb){
    uint2 pv = *(const uint2*)(Pb + off);
    r0 -= __builtin_bit_cast(h2, pv.x);
    r1 -= __builtin_bit_cast(h2, pv.y);
  }
  uint2 ob;
  ob.x = __builtin_bit_cast(unsigned, r0);
  ob.y = __builtin_bit_cast(unsigned, r1);
  *(uint2*)(tx + off) = ob;
}

// fp32 [rows][C] -> f16 strided slot (layer-1 input only)
template<int C>
__global__ void k_f2h(const float* __restrict__ X, _Float16* __restrict__ tx,
                      int tx_stride){
  int idx = blockIdx.x * blockDim.x + threadIdx.x;
  const int GPR = C / 4;
  if(idx < N_NODES * GPR){
    int r = idx / GPR;
    int c = (idx - r * GPR) * 4;
    float4 v = *(const float4*)(X + (size_t)r * C + c);
    h2 p0 = {(_Float16)v.x, (_Float16)v.y};
    h2 p1 = {(_Float16)v.z, (_Float16)v.w};
    uint2 ob;
    ob.x = __builtin_bit_cast(unsigned, p0);
    ob.y = __builtin_bit_cast(unsigned, p1);
    *(uint2*)(tx + (size_t)r * tx_stride + c) = ob;
  }
}

// LDS-tiled weight transpose: WT[o][kc] = (f16)W[kc][o], W is [R][256].
__global__ __launch_bounds__(256) void k_wt3t(const float* __restrict__ W0, _Float16* __restrict__ WT0,
                                              const float* __restrict__ W1, _Float16* __restrict__ WT1,
                                              const float* __restrict__ W2, _Float16* __restrict__ WT2){
  __shared__ float t[32][33];
  int b = blockIdx.x;
  const float* W; _Float16* WT; int R; int tb;
  if(b < 320){ W = W0; WT = WT0; R = 1280; tb = b; }
  else if(b < 960){ W = W1; WT = WT1; R = 2560; tb = b - 320; }
  else { W = W2; WT = WT2; R = 2560; tb = b - 960; }
  int tr = tb >> 3, tc = tb & 7;
  int tx = threadIdx.x & 31, ty = threadIdx.x >> 5;
#pragma unroll
  for(int i = 0; i < 4; i++){
    int r = tr * 32 + ty + 8 * i;
    t[ty + 8 * i][tx] = W[(size_t)r * 256 + tc * 32 + tx];
  }
  __syncthreads();
#pragma unroll
  for(int i = 0; i < 4; i++){
    int o = tc * 32 + ty + 8 * i;
    WT[(size_t)o * R + tr * 32 + tx] = (_Float16)t[tx][ty + 8 * i];
  }
}

// ---------------- MFMA GEMM (f16) 64x64, XCD-pinned, single-sync dbuf ------
// PROVEN shape (round-2): 640 blocks = 2.5 blocks/CU, 32KB LDS, 0 bank
// conflicts. Round-4's BM=128 variant dropped occupancy to 1 block/CU and
// regressed 60% — do not enlarge tiles with N=256.

__global__ __launch_bounds__(256) void k_gemm_f(const _Float16* __restrict__ A,
                                                const _Float16* __restrict__ BT,
                                                const float* __restrict__ bias,
                                                float* __restrict__ H,
                                                _Float16* __restrict__ tx2,
                                                int M, int Ktot){
  int b = blockIdx.x;
  int xcd = b & 7;
  int l = b >> 3;
  int m = xcd + 8 * (l >> 2);
  int n = l & 3;
  if(m * 64 >= M) return;
  int row0 = m * 64, col0 = n * 64;

  __shared__ short As[2][64 * 64];
  __shared__ short Bs[2][64 * 64];
  int tid = threadIdx.x;
  int lane = tid & 63;
  int wave = tid >> 6;
  int l15 = lane & 15;
  int quad = lane >> 4;
  int wm = (wave & 1) * 32;
  int wn = (wave >> 1) * 32;

  int e0 = tid, e1 = tid + 256;
  int r0 = e0 >> 3, g0 = e0 & 7;
  int r1 = e1 >> 3, g1 = e1 & 7;
  int gr0 = row0 + r0, gr1 = row0 + r1;
  int sa0 = r0 * 64 + ((g0 ^ (r0 & 7)) * 8);
  int sa1 = r1 * 64 + ((g1 ^ (r1 & 7)) * 8);

  f32x4 acc[2][2] = {};
  uint4 av0, av1, bv0, bv1;

  auto load = [&](int k0){
    av0 = (gr0 < M) ? *(const uint4*)(A + (size_t)gr0 * Ktot + k0 + g0 * 8)
                    : make_uint4(0u, 0u, 0u, 0u);
    av1 = (gr1 < M) ? *(const uint4*)(A + (size_t)gr1 * Ktot + k0 + g1 * 8)
                    : make_uint4(0u, 0u, 0u, 0u);
    bv0 = *(const uint4*)(BT + (size_t)(col0 + r0) * Ktot + k0 + g0 * 8);
    bv1 = *(const uint4*)(BT + (size_t)(col0 + r1) * Ktot + k0 + g1 * 8);
  };
  auto stor = [&](int buf){
    *(uint4*)(&As[buf][sa0]) = av0;
    *(uint4*)(&As[buf][sa1]) = av1;
    *(uint4*)(&Bs[buf][sa0]) = bv0;
    *(uint4*)(&Bs[buf][sa1]) = bv1;
  };

  load(0);
  stor(0);
  __syncthreads();
  int nk = Ktot >> 6;
  for(int it = 0; it < nk; it++){
    int cur = it & 1;
    if(it + 1 < nk) load((it + 1) << 6);   // in flight across MFMAs
#pragma unroll
    for(int kk = 0; kk < 64; kk += 32){
      int g = (kk >> 3) + quad;
      half8 a[2], bb[2];
#pragma unroll
      for(int mi = 0; mi < 2; mi++){
        int r = wm + mi * 16 + l15;
        a[mi] = *(const half8*)(&As[cur][r * 64 + ((g ^ (r & 7)) * 8)]);
      }
#pragma unroll
      for(int ni = 0; ni < 2; ni++){
        int nn = wn + ni * 16 + l15;
        bb[ni] = *(const half8*)(&Bs[cur][nn * 64 + ((g ^ (nn & 7)) * 8)]);
      }
#pragma unroll
      for(int mi = 0; mi < 2; mi++)
#pragma unroll
        for(int ni = 0; ni < 2; ni++)
          acc[mi][ni] = __builtin_amdgcn_mfma_f32_16x16x32_f16(a[mi], bb[ni], acc[mi][ni], 0, 0, 0);
    }
    if(it + 1 < nk){
      stor(cur ^ 1);
      __syncthreads();
    }
  }

  const int K256 = KCHEB * C_HID;
#pragma unroll
  for(int mi = 0; mi < 2; mi++){
#pragma unroll
    for(int ni = 0; ni < 2; ni++){
      int gcol = col0 + wn + ni * 16 + l15;
      float bv = bias[gcol];
#pragma unroll
      for(int r = 0; r < 4; r++){
        int grow = row0 + wm + mi * 16 + quad * 4 + r;
        if(grow < M){
          float v = fmaxf(acc[mi][ni][r] + bv, 0.f);
          if(tx2) tx2[(size_t)grow * K256 + gcol] = (_Float16)v;
          else    H[(size_t)grow * C_HID + gcol] = v;
        }
      }
    }
  }
}

// ---------------- pooling + head ----------------

__global__ __launch_bounds__(256) void k_pool2(const float* __restrict__ h,
                                               const int* __restrict__ batch,
                                               float* __restrict__ gsum){
  int c  = threadIdx.x;
  int n0 = blockIdx.x * POOL_CHUNK;
  int n1 = n0 + POOL_CHUNK;
  if(n1 > N_NODES) n1 = N_NODES;
  if(n0 >= n1) return;
  float acc = 0.f;
  int cur = batch[n0];
  for(int n = n0; n < n1; n++){
    int g = batch[n];
    if(g != cur){
      atomicAdd(&gsum[cur * C_HID + c], acc);
      acc = 0.f;
      cur = g;
    }
    acc += h[(size_t)n * C_HID + c];
  }
  atomicAdd(&gsum[cur * C_HID + c], acc);
}

__global__ __launch_bounds__(128) void k_final(const float* __restrict__ gsum,
                                               const int* __restrict__ gcnt,
                                               const float* __restrict__ Wout,
                                               const float* __restrict__ bout,
                                               float* __restrict__ out){
  int g = blockIdx.x;
  int o = threadIdx.x;
  float inv = 1.f / fmaxf((float)gcnt[g], 1.f);
  float acc = bout[o];
  for(int c = 0; c < C_HID; c++) acc += gsum[g * C_HID + c] * inv * Wout[c * C_OUTC + o];
  out[g * C_OUTC + o] = acc;
}

// ---------------- host ----------------

extern "C" void kernel_launch(void* const* d_in, const int* in_sizes, int n_in,
                              void* d_out, int out_size, void* d_ws, size_t ws_size,
                              hipStream_t stream){
  const float* x    = (const float*)d_in[0];
  const float* W0   = (const float*)d_in[1];
  const float* b0   = (const float*)d_in[2];
  const float* W1   = (const float*)d_in[3];
  const float* b1   = (const float*)d_in[4];
  const float* W2   = (const float*)d_in[5];
  const float* b2   = (const float*)d_in[6];
  const float* Wout = (const float*)d_in[7];
  const float* bout = (const float*)d_in[8];
  const int*   ei   = (const int*)d_in[9];
  const int*   batch= (const int*)d_in[10];
  const int* src = ei;
  const int* dst = ei + N_EDGES;
  float* out = (float*)d_out;

  char* p = (char*)d_ws;
  auto alloc = [&](size_t bytes)->char*{ char* r = p; p += align_up(bytes, 256); return r; };

  int*   deg    = (int*)  alloc(N_NODES * 4);
  int*   indeg  = (int*)  alloc(N_NODES * 4);
  int*   offs   = (int*)  alloc((N_NODES + 1) * 4);
  int*   cursor = (int*)  alloc(N_NODES * 4);
  float* dis    = (float*)alloc(N_NODES * 4);
  int*   perm   = (int*)  alloc(N_NODES * 4);
  int*   csr_s  = (int*)  alloc(N_EDGES * 4);
  unsigned* csr_wp = (unsigned*)alloc(N_EDGES * 4);
  int*   gcnt   = (int*)  alloc(N_GRAPHS * 4);
  int*   gstart = (int*)  alloc((N_GRAPHS + 1) * 4);
  float* gsum   = (float*)alloc(N_GRAPHS * C_HID * 4);

  const size_t txBytes = (size_t)N_NODES * (KCHEB * C_HID) * 2;  // 51.2 MB
  _Float16* txP = (_Float16*)alloc(txBytes);
  _Float16* txQ = (_Float16*)alloc(txBytes);
  _Float16* WT0 = (_Float16*)alloc((size_t)KCHEB * C_IN  * C_HID * 2);
  _Float16* WT1 = (_Float16*)alloc((size_t)KCHEB * C_HID * C_HID * 2);
  _Float16* WT2 = (_Float16*)alloc((size_t)KCHEB * C_HID * C_HID * 2);
  float* Hb = (float*)alloc((size_t)N_NODES * C_HID * 4);

  hipMemsetAsync(deg,   0, N_NODES * 4, stream);
  hipMemsetAsync(indeg, 0, N_NODES * 4, stream);
  hipMemsetAsync(gsum,  0, N_GRAPHS * C_HID * 4, stream);

  const int TB = 256;
  int egrid = (N_EDGES + TB - 1) / TB;

  k_deg<<<egrid, TB, 0, stream>>>(src, dst, deg, indeg);
  k_scan<<<1, 1024, 0, stream>>>(indeg, offs, cursor, deg, dis, perm);
  k_scatter<<<egrid, TB, 0, stream>>>(src, dst, dis, cursor, csr_s, csr_wp);
  k_gbounds<<<1, 128, 0, stream>>>(batch, gstart, gcnt);
  k_wt3t<<<1600, 256, 0, stream>>>(W0, WT0, W1, WT1, W2, WT2);

  const int K128 = KCHEB * C_IN;   // 1280
  const int K256 = KCHEB * C_HID;  // 2560
  const int GEMM_BLOCKS = 640;     // proven 64x64 shape
  const int PROP_H_BLOCKS = 1256;  // 2 halves x 625 groups, XCD-interleaved
  const int PROP_1_BLOCKS = N_NODES / 8;  // 1250

  // ---- layer 1 (Cin=128, A in txP with stride K128) ----
  {
    int ng = N_NODES * (C_IN / 4);
    k_f2h<C_IN><<<(ng + TB - 1) / TB, TB, 0, stream>>>(x, txP, K128);
    for(int k = 1; k < KCHEB; k++){
      const _Float16* Xb = txP + (size_t)(k - 1) * C_IN;
      const _Float16* Pb = (k >= 2) ? txP + (size_t)(k - 2) * C_IN : nullptr;
      _Float16* tx = txP + (size_t)k * C_IN;
      k_prop128<<<PROP_1_BLOCKS, 256, 0, stream>>>(Xb, Pb, tx, csr_s, csr_wp, offs, perm,
                                                   k == 1 ? 1.f : 2.f);
    }
    k_gemm_f<<<GEMM_BLOCKS, 256, 0, stream>>>(txP, WT0, b0, nullptr, txQ, N_NODES, K128);
  }

  // ---- layer 2 (A in txQ, stride K256) -> f16 slot 0 of txP ----
  {
    for(int k = 1; k < KCHEB; k++){
      const _Float16* Xb = txQ + (size_t)(k - 1) * C_HID;
      const _Float16* Pb = (k >= 2) ? txQ + (size_t)(k - 2) * C_HID : nullptr;
      _Float16* tx = txQ + (size_t)k * C_HID;
      k_prop256h<<<PROP_H_BLOCKS, 256, 0, stream>>>(Xb, Pb, tx, csr_s, csr_wp, offs, perm,
                                                    k == 1 ? 1.f : 2.f);
    }
    k_gemm_f<<<GEMM_BLOCKS, 256, 0, stream>>>(txQ, WT1, b1, nullptr, txP, N_NODES, K256);
  }

  // ---- layer 3 (A in txP, stride K256) -> fp32 Hb ----
  {
    for(int k = 1; k < KCHEB; k++){
      const _Float16* Xb = txP + (size_t)(k - 1) * C_HID;
      const _Float16* Pb = (k >= 2) ? txP + (size_t)(k - 2) * C_HID : nullptr;
      _Float16* tx = txP + (size_t)k * C_HID;
      k_prop256h<<<PROP_H_BLOCKS, 256, 0, stream>>>(Xb, Pb, tx, csr_s, csr_wp, offs, perm,
                                                    k == 1 ? 1.f : 2.f);
    }
    k_gemm_f<<<GEMM_BLOCKS, 256, 0, stream>>>(txP, WT2, b2, Hb, nullptr, N_NODES, K256);
  }

  k_pool2<<<(N_NODES + POOL_CHUNK - 1) / POOL_CHUNK, 256, 0, stream>>>(Hb, batch, gsum);
  k_final<<<N_GRAPHS, C_OUTC, 0, stream>>>(gsum, gcnt, Wout, bout, out);
}

// Round 7
// 615.424 us; speedup vs baseline: 7.2927x; 1.0186x over previous
//
#include <hip/hip_runtime.h>
#include <cstdint>
#include <cstddef>

#define N_NODES 10000
#define N_EDGES 320000
#define N_GRAPHS 64
#define KCHEB 10
#define C_IN 128
#define C_HID 256
#define C_OUTC 128

static inline size_t align_up(size_t v, size_t a){ return (v + a - 1) / a * a; }

typedef __attribute__((ext_vector_type(8))) _Float16 half8;
typedef __attribute__((ext_vector_type(2))) _Float16 h2;
typedef __attribute__((ext_vector_type(4))) float f32x4;

// ---------------- graph setup kernels ----------------

__global__ void k_deg(const int* __restrict__ src, const int* __restrict__ dst,
                      int* __restrict__ deg, int* __restrict__ indeg){
  int e = blockIdx.x*blockDim.x + threadIdx.x;
  if(e < N_EDGES){
    atomicAdd(&deg[src[e]], 1);
    atomicAdd(&indeg[dst[e]], 1);
  }
}

// scan(indeg)->offs/cursor, dis=rsqrt(deg), counting sort by in-degree
// (descending) -> perm, AND graph bounds (folded k_gbounds: threads 0..64
// binary-search the sorted batch array).
__global__ __launch_bounds__(1024) void k_scan(const int* __restrict__ cnt,
                                               int* __restrict__ offs,
                                               int* __restrict__ cursor,
                                               const int* __restrict__ deg,
                                               float* __restrict__ dis,
                                               int* __restrict__ perm,
                                               const int* __restrict__ batch,
                                               int* __restrict__ gstart,
                                               int* __restrict__ gcnt){
  __shared__ int part[1024];
  __shared__ int hist[256];
  __shared__ int hoff[256];
  const int n = N_NODES;
  const int CH = (n + 1023) / 1024;
  int tid = threadIdx.x;
  int base = tid * CH;
  if(tid < 256) hist[tid] = 0;
  if(tid <= N_GRAPHS){
    int lo = 0, hi = N_NODES;
    while(lo < hi){
      int mid = (lo + hi) >> 1;
      if(batch[mid] < tid) lo = mid + 1; else hi = mid;
    }
    gstart[tid] = lo;
  }
  int s = 0;
  for(int i = 0; i < CH; i++){
    int idx = base + i;
    if(idx < n){
      s += cnt[idx];
      int d = deg[idx];
      dis[idx] = d > 0 ? rsqrtf((float)d) : 0.f;
    }
  }
  part[tid] = s;
  __syncthreads();
  if(tid < N_GRAPHS) gcnt[tid] = gstart[tid + 1] - gstart[tid];
  for(int off = 1; off < 1024; off <<= 1){
    int v = (tid >= off) ? part[tid - off] : 0;
    __syncthreads();
    part[tid] += v;
    __syncthreads();
  }
  int run = (tid == 0) ? 0 : part[tid - 1];
  for(int i = 0; i < CH; i++){
    int idx = base + i;
    if(idx < n){
      offs[idx] = run;
      cursor[idx] = run;
      run += cnt[idx];
      int d = cnt[idx]; if(d > 255) d = 255;
      atomicAdd(&hist[d], 1);
    }
  }
  if(tid == 1023) offs[n] = part[1023];
  __syncthreads();
  if(tid == 0){
    int r2 = 0;
    for(int d = 255; d >= 0; d--){ hoff[d] = r2; r2 += hist[d]; }
  }
  __syncthreads();
  for(int i = 0; i < CH; i++){
    int idx = base + i;
    if(idx < n){
      int d = cnt[idx]; if(d > 255) d = 255;
      int p0 = atomicAdd(&hoff[d], 1);
      perm[p0] = idx;
    }
  }
}

__global__ void k_scatter(const int* __restrict__ src, const int* __restrict__ dst,
                          const float* __restrict__ dis, int* __restrict__ cursor,
                          int* __restrict__ csr_s, unsigned* __restrict__ csr_wp){
  int e = blockIdx.x*blockDim.x + threadIdx.x;
  if(e < N_EDGES){
    int s = src[e], d = dst[e];
    float w = -dis[s] * dis[d];
    unsigned short wb = __builtin_bit_cast(unsigned short, (_Float16)w);
    int p = atomicAdd(&cursor[d], 1);
    csr_s[p] = s;
    csr_wp[p] = (unsigned)wb * 0x00010001u;
  }
}

// ---------------- propagation (f16 state, v_pk_fma_f16, degree-sorted) -----

__device__ inline void hfma4(h2* a, uint4 v, unsigned wbits){
  h2 w2 = __builtin_bit_cast(h2, wbits);
  a[0] += __builtin_bit_cast(h2, v.x) * w2;
  a[1] += __builtin_bit_cast(h2, v.y) * w2;
  a[2] += __builtin_bit_cast(h2, v.z) * w2;
  a[3] += __builtin_bit_cast(h2, v.w) * w2;
}

// 256-ch propagation, channel-split halves pinned to XCD groups (bid%8 ->
// XCD; 0-3 = half0, 4-7 = half1): per-XCD gather working set 2.56 MB < 4 MB
// L2. 16-lane groups own one node-half; nodes assigned via degree-sorted perm.
__global__ __launch_bounds__(256) void k_prop256h(const _Float16* __restrict__ Xb,
                                                  const _Float16* __restrict__ Pb,
                                                  _Float16* __restrict__ tx,
                                                  const int* __restrict__ csr_s,
                                                  const unsigned* __restrict__ csr_wp,
                                                  const int* __restrict__ offs,
                                                  const int* __restrict__ perm,
                                                  float alpha){
  const int stride  = KCHEB * C_HID;
  const int strideB = stride * 2;        // 5120 bytes
  int bid  = blockIdx.x;
  int half = (bid >> 2) & 1;
  int lh   = (bid >> 3) * 4 + (bid & 3);
  int l15  = threadIdx.x & 15;
  int lane = threadIdx.x & 63;
  int b16  = lane & 48;
  int e8   = l15 & 7;
  int nidx = lh * 16 + (threadIdx.x >> 4);
  if(nidx >= N_NODES) return;
  int node = perm[nidx];
  int j0 = offs[node], j1 = offs[node + 1];
  h2 a[4] = {};
  const char* __restrict__ gbase = (const char*)Xb + (half * (C_HID/2) + l15 * 8) * 2;
  int j = j0;
  int sv = 0; unsigned wv = 0;
  bool have = (j + 7 < j1);
  if(have){ sv = csr_s[j + e8] * strideB; wv = csr_wp[j + e8]; }
  while(have){
    int jn = j + 8;
    bool more = (jn + 7 < j1);
    int sv2 = 0; unsigned wv2 = 0;
    if(more){ sv2 = csr_s[jn + e8] * strideB; wv2 = csr_wp[jn + e8]; }
    uint4 v[8];
#pragma unroll
    for(int i = 0; i < 8; i++){
      int si = __shfl(sv, b16 + i);
      v[i] = *(const uint4*)(gbase + si);
    }
#pragma unroll
    for(int i = 0; i < 8; i++){
      unsigned wi = (unsigned)__shfl((int)wv, b16 + i);
      hfma4(a, v[i], wi);
    }
    sv = sv2; wv = wv2; j = jn; have = more;
  }
  for(; j < j1; j++){
    int si = csr_s[j] * strideB;
    uint4 v0 = *(const uint4*)(gbase + si);
    hfma4(a, v0, csr_wp[j]);
  }
  _Float16 ah = (_Float16)alpha;
  h2 al = {ah, ah};
  h2 r[4];
#pragma unroll
  for(int i = 0; i < 4; i++) r[i] = a[i] * al;
  size_t off = (size_t)node * stride + half * (C_HID/2) + l15 * 8;
  if(Pb){
    uint4 pv = *(const uint4*)(Pb + off);
    r[0] -= __builtin_bit_cast(h2, pv.x);
    r[1] -= __builtin_bit_cast(h2, pv.y);
    r[2] -= __builtin_bit_cast(h2, pv.z);
    r[3] -= __builtin_bit_cast(h2, pv.w);
  }
  uint4 ob;
  ob.x = __builtin_bit_cast(unsigned, r[0]);
  ob.y = __builtin_bit_cast(unsigned, r[1]);
  ob.z = __builtin_bit_cast(unsigned, r[2]);
  ob.w = __builtin_bit_cast(unsigned, r[3]);
  *(uint4*)(tx + off) = ob;
}

__global__ __launch_bounds__(256) void k_prop128(const _Float16* __restrict__ Xb,
                                                 const _Float16* __restrict__ Pb,
                                                 _Float16* __restrict__ tx,
                                                 const int* __restrict__ csr_s,
                                                 const unsigned* __restrict__ csr_wp,
                                                 const int* __restrict__ offs,
                                                 const int* __restrict__ perm,
                                                 float alpha){
  const int stride  = KCHEB * C_IN;      // 1280 elements
  const int strideB = stride * 2;        // 2560 bytes
  int hl   = threadIdx.x & 31;
  int b32  = threadIdx.x & 32;
  int e8   = hl & 7;
  int node = perm[blockIdx.x * 8 + (threadIdx.x >> 5)];
  int j0 = offs[node], j1 = offs[node + 1];
  h2 a[2] = {};
  const char* __restrict__ gbase = (const char*)Xb + hl * 8;
  int j = j0;
  int sv = 0; unsigned wv = 0;
  bool have = (j + 7 < j1);
  if(have){ sv = csr_s[j + e8] * strideB; wv = csr_wp[j + e8]; }
  while(have){
    int jn = j + 8;
    bool more = (jn + 7 < j1);
    int sv2 = 0; unsigned wv2 = 0;
    if(more){ sv2 = csr_s[jn + e8] * strideB; wv2 = csr_wp[jn + e8]; }
    uint2 v[8];
#pragma unroll
    for(int i = 0; i < 8; i++){
      int si = __shfl(sv, b32 + i);
      v[i] = *(const uint2*)(gbase + si);
    }
#pragma unroll
    for(int i = 0; i < 8; i++){
      unsigned wi = (unsigned)__shfl((int)wv, b32 + i);
      h2 w2 = __builtin_bit_cast(h2, wi);
      a[0] += __builtin_bit_cast(h2, v[i].x) * w2;
      a[1] += __builtin_bit_cast(h2, v[i].y) * w2;
    }
    sv = sv2; wv = wv2; j = jn; have = more;
  }
  for(; j < j1; j++){
    int si = csr_s[j] * strideB;
    h2 w2 = __builtin_bit_cast(h2, csr_wp[j]);
    uint2 v0 = *(const uint2*)(gbase + si);
    a[0] += __builtin_bit_cast(h2, v0.x) * w2;
    a[1] += __builtin_bit_cast(h2, v0.y) * w2;
  }
  _Float16 ah = (_Float16)alpha;
  h2 al = {ah, ah};
  h2 r0 = a[0] * al, r1 = a[1] * al;
  size_t off = (size_t)node * stride + hl * 4;
  if(Pb){
    uint2 pv = *(const uint2*)(Pb + off);
    r0 -= __builtin_bit_cast(h2, pv.x);
    r1 -= __builtin_bit_cast(h2, pv.y);
  }
  uint2 ob;
  ob.x = __builtin_bit_cast(unsigned, r0);
  ob.y = __builtin_bit_cast(unsigned, r1);
  *(uint2*)(tx + off) = ob;
}

// ---------------- fused prep: weight transposes + x->f16 (k_f2h folded) ----
// blocks 0..1599: WT[o][kc] = (f16)W[kc][o] (LDS-tiled). blocks 1600..2849:
// convert x fp32 -> f16 into txP slot 0 (stride 1280).
__global__ __launch_bounds__(256) void k_prep(const float* __restrict__ W0, _Float16* __restrict__ WT0,
                                              const float* __restrict__ W1, _Float16* __restrict__ WT1,
                                              const float* __restrict__ W2, _Float16* __restrict__ WT2,
                                              const float* __restrict__ X, _Float16* __restrict__ txP){
  int b = blockIdx.x;
  if(b >= 1600){
    int idx = (b - 1600) * 256 + threadIdx.x;
    if(idx < N_NODES * (C_IN / 4)){
      int r = idx >> 5;                 // C_IN/4 = 32
      int c = (idx & 31) * 4;
      float4 v = *(const float4*)(X + (size_t)r * C_IN + c);
      h2 p0 = {(_Float16)v.x, (_Float16)v.y};
      h2 p1 = {(_Float16)v.z, (_Float16)v.w};
      uint2 ob;
      ob.x = __builtin_bit_cast(unsigned, p0);
      ob.y = __builtin_bit_cast(unsigned, p1);
      *(uint2*)(txP + (size_t)r * (KCHEB * C_IN) + c) = ob;
    }
    return;
  }
  __shared__ float t[32][33];
  const float* W; _Float16* WT; int R; int tb;
  if(b < 320){ W = W0; WT = WT0; R = 1280; tb = b; }
  else if(b < 960){ W = W1; WT = WT1; R = 2560; tb = b - 320; }
  else { W = W2; WT = WT2; R = 2560; tb = b - 960; }
  int tr = tb >> 3, tc = tb & 7;
  int tx = threadIdx.x & 31, ty = threadIdx.x >> 5;
#pragma unroll
  for(int i = 0; i < 4; i++){
    int r = tr * 32 + ty + 8 * i;
    t[ty + 8 * i][tx] = W[(size_t)r * 256 + tc * 32 + tx];
  }
  __syncthreads();
#pragma unroll
  for(int i = 0; i < 4; i++){
    int o = tc * 32 + ty + 8 * i;
    WT[(size_t)o * R + tr * 32 + tx] = (_Float16)t[tx][ty + 8 * i];
  }
}

// ---------------- MFMA GEMM (f16) 64x64, XCD-pinned, single-sync dbuf ------
// PROVEN shape (round-2/5): 640 blocks, 32KB LDS, 0 bank conflicts. If
// tx2 != null: write relu(A@B+bias) f16 to tx2 (next layer's Tx0). Else
// (layer 3): POOLED epilogue — stage ReLU tile in LDS (reuses As, 16 KB),
// per-column run-reduce over sorted batch ids, atomicAdd into gsum.
// Removes k_pool2 dispatch + the 20 MB Hb fp32 round-trip.

__global__ __launch_bounds__(256) void k_gemm_f(const _Float16* __restrict__ A,
                                                const _Float16* __restrict__ BT,
                                                const float* __restrict__ bias,
                                                _Float16* __restrict__ tx2,
                                                const int* __restrict__ batch,
                                                float* __restrict__ gsum,
                                                int M, int Ktot){
  int b = blockIdx.x;
  int xcd = b & 7;
  int l = b >> 3;
  int m = xcd + 8 * (l >> 2);
  int n = l & 3;
  if(m * 64 >= M) return;
  int row0 = m * 64, col0 = n * 64;

  __shared__ short As[2][64 * 64];
  __shared__ short Bs[2][64 * 64];
  int tid = threadIdx.x;
  int lane = tid & 63;
  int wave = tid >> 6;
  int l15 = lane & 15;
  int quad = lane >> 4;
  int wm = (wave & 1) * 32;
  int wn = (wave >> 1) * 32;

  int e0 = tid, e1 = tid + 256;
  int r0 = e0 >> 3, g0 = e0 & 7;
  int r1 = e1 >> 3, g1 = e1 & 7;
  int gr0 = row0 + r0, gr1 = row0 + r1;
  int sa0 = r0 * 64 + ((g0 ^ (r0 & 7)) * 8);
  int sa1 = r1 * 64 + ((g1 ^ (r1 & 7)) * 8);

  f32x4 acc[2][2] = {};
  uint4 av0, av1, bv0, bv1;

  auto load = [&](int k0){
    av0 = (gr0 < M) ? *(const uint4*)(A + (size_t)gr0 * Ktot + k0 + g0 * 8)
                    : make_uint4(0u, 0u, 0u, 0u);
    av1 = (gr1 < M) ? *(const uint4*)(A + (size_t)gr1 * Ktot + k0 + g1 * 8)
                    : make_uint4(0u, 0u, 0u, 0u);
    bv0 = *(const uint4*)(BT + (size_t)(col0 + r0) * Ktot + k0 + g0 * 8);
    bv1 = *(const uint4*)(BT + (size_t)(col0 + r1) * Ktot + k0 + g1 * 8);
  };
  auto stor = [&](int buf){
    *(uint4*)(&As[buf][sa0]) = av0;
    *(uint4*)(&As[buf][sa1]) = av1;
    *(uint4*)(&Bs[buf][sa0]) = bv0;
    *(uint4*)(&Bs[buf][sa1]) = bv1;
  };

  load(0);
  stor(0);
  __syncthreads();
  int nk = Ktot >> 6;
  for(int it = 0; it < nk; it++){
    int cur = it & 1;
    if(it + 1 < nk) load((it + 1) << 6);   // in flight across MFMAs
#pragma unroll
    for(int kk = 0; kk < 64; kk += 32){
      int g = (kk >> 3) + quad;
      half8 a[2], bb[2];
#pragma unroll
      for(int mi = 0; mi < 2; mi++){
        int r = wm + mi * 16 + l15;
        a[mi] = *(const half8*)(&As[cur][r * 64 + ((g ^ (r & 7)) * 8)]);
      }
#pragma unroll
      for(int ni = 0; ni < 2; ni++){
        int nn = wn + ni * 16 + l15;
        bb[ni] = *(const half8*)(&Bs[cur][nn * 64 + ((g ^ (nn & 7)) * 8)]);
      }
#pragma unroll
      for(int mi = 0; mi < 2; mi++)
#pragma unroll
        for(int ni = 0; ni < 2; ni++)
          acc[mi][ni] = __builtin_amdgcn_mfma_f32_16x16x32_f16(a[mi], bb[ni], acc[mi][ni], 0, 0, 0);
    }
    if(it + 1 < nk){
      stor(cur ^ 1);
      __syncthreads();
    }
  }

  if(tx2){
    const int K256 = KCHEB * C_HID;
#pragma unroll
    for(int mi = 0; mi < 2; mi++){
#pragma unroll
      for(int ni = 0; ni < 2; ni++){
        int gcol = col0 + wn + ni * 16 + l15;
        float bv = bias[gcol];
#pragma unroll
        for(int r = 0; r < 4; r++){
          int grow = row0 + wm + mi * 16 + quad * 4 + r;
          if(grow < M){
            float v = fmaxf(acc[mi][ni][r] + bv, 0.f);
            tx2[(size_t)grow * K256 + gcol] = (_Float16)v;
          }
        }
      }
    }
  } else {
    // pooled epilogue (layer 3): LDS-stage 64x64 fp32 tile, column run-reduce
    __syncthreads();                       // main-loop LDS readers done
    float* Ls = (float*)As;                // 64*64*4 = 16 KB = sizeof(As)
#pragma unroll
    for(int mi = 0; mi < 2; mi++){
#pragma unroll
      for(int ni = 0; ni < 2; ni++){
        int lc = wn + ni * 16 + l15;
        float bv = bias[col0 + lc];
#pragma unroll
        for(int r = 0; r < 4; r++){
          int lr = wm + mi * 16 + quad * 4 + r;
          Ls[lr * 64 + lc] = fmaxf(acc[mi][ni][r] + bv, 0.f);
        }
      }
    }
    __syncthreads();
    int col  = tid & 63;
    int rseg = tid >> 6;                   // 0..3, 16 rows each
    int rb   = rseg * 16;
    float accp = 0.f;
    int curg = -1;
    for(int rr = 0; rr < 16; rr++){
      int grow = row0 + rb + rr;
      if(grow >= M) break;
      int g = batch[grow];
      if(g != curg){
        if(curg >= 0) atomicAdd(&gsum[curg * C_HID + col0 + col], accp);
        accp = 0.f; curg = g;
      }
      accp += Ls[(rb + rr) * 64 + col];
    }
    if(curg >= 0) atomicAdd(&gsum[curg * C_HID + col0 + col], accp);
  }
}

// ---------------- head ----------------

__global__ __launch_bounds__(128) void k_final(const float* __restrict__ gsum,
                                               const int* __restrict__ gcnt,
                                               const float* __restrict__ Wout,
                                               const float* __restrict__ bout,
                                               float* __restrict__ out){
  int g = blockIdx.x;
  int o = threadIdx.x;
  float inv = 1.f / fmaxf((float)gcnt[g], 1.f);
  float acc = bout[o];
  for(int c = 0; c < C_HID; c++) acc += gsum[g * C_HID + c] * inv * Wout[c * C_OUTC + o];
  out[g * C_OUTC + o] = acc;
}

// ---------------- host ----------------

extern "C" void kernel_launch(void* const* d_in, const int* in_sizes, int n_in,
                              void* d_out, int out_size, void* d_ws, size_t ws_size,
                              hipStream_t stream){
  const float* x    = (const float*)d_in[0];
  const float* W0   = (const float*)d_in[1];
  const float* b0   = (const float*)d_in[2];
  const float* W1   = (const float*)d_in[3];
  const float* b1   = (const float*)d_in[4];
  const float* W2   = (const float*)d_in[5];
  const float* b2   = (const float*)d_in[6];
  const float* Wout = (const float*)d_in[7];
  const float* bout = (const float*)d_in[8];
  const int*   ei   = (const int*)d_in[9];
  const int*   batch= (const int*)d_in[10];
  const int* src = ei;
  const int* dst = ei + N_EDGES;
  float* out = (float*)d_out;

  char* p = (char*)d_ws;
  auto alloc = [&](size_t bytes)->char*{ char* r = p; p += align_up(bytes, 256); return r; };

  int*   deg    = (int*)  alloc(N_NODES * 4);
  int*   indeg  = (int*)  alloc(N_NODES * 4);
  int*   offs   = (int*)  alloc((N_NODES + 1) * 4);
  int*   cursor = (int*)  alloc(N_NODES * 4);
  float* dis    = (float*)alloc(N_NODES * 4);
  int*   perm   = (int*)  alloc(N_NODES * 4);
  int*   csr_s  = (int*)  alloc(N_EDGES * 4);
  unsigned* csr_wp = (unsigned*)alloc(N_EDGES * 4);
  int*   gcnt   = (int*)  alloc(N_GRAPHS * 4);
  int*   gstart = (int*)  alloc((N_GRAPHS + 1) * 4);
  float* gsum   = (float*)alloc(N_GRAPHS * C_HID * 4);

  const size_t txBytes = (size_t)N_NODES * (KCHEB * C_HID) * 2;  // 51.2 MB
  _Float16* txP = (_Float16*)alloc(txBytes);
  _Float16* txQ = (_Float16*)alloc(txBytes);
  _Float16* WT0 = (_Float16*)alloc((size_t)KCHEB * C_IN  * C_HID * 2);
  _Float16* WT1 = (_Float16*)alloc((size_t)KCHEB * C_HID * C_HID * 2);
  _Float16* WT2 = (_Float16*)alloc((size_t)KCHEB * C_HID * C_HID * 2);

  hipMemsetAsync(deg,   0, N_NODES * 4, stream);
  hipMemsetAsync(indeg, 0, N_NODES * 4, stream);
  hipMemsetAsync(gsum,  0, N_GRAPHS * C_HID * 4, stream);

  const int TB = 256;
  int egrid = (N_EDGES + TB - 1) / TB;

  k_deg<<<egrid, TB, 0, stream>>>(src, dst, deg, indeg);
  k_scan<<<1, 1024, 0, stream>>>(indeg, offs, cursor, deg, dis, perm, batch, gstart, gcnt);
  k_scatter<<<egrid, TB, 0, stream>>>(src, dst, dis, cursor, csr_s, csr_wp);
  k_prep<<<2850, 256, 0, stream>>>(W0, WT0, W1, WT1, W2, WT2, x, txP);

  const int K128 = KCHEB * C_IN;   // 1280
  const int K256 = KCHEB * C_HID;  // 2560
  const int GEMM_BLOCKS = 640;     // proven 64x64 shape
  const int PROP_H_BLOCKS = 1256;  // 2 halves x 625 groups, XCD-interleaved
  const int PROP_1_BLOCKS = N_NODES / 8;  // 1250

  // ---- layer 1 (Cin=128, A in txP with stride K128) ----
  {
    for(int k = 1; k < KCHEB; k++){
      const _Float16* Xb = txP + (size_t)(k - 1) * C_IN;
      const _Float16* Pb = (k >= 2) ? txP + (size_t)(k - 2) * C_IN : nullptr;
      _Float16* tx = txP + (size_t)k * C_IN;
      k_prop128<<<PROP_1_BLOCKS, 256, 0, stream>>>(Xb, Pb, tx, csr_s, csr_wp, offs, perm,
                                                   k == 1 ? 1.f : 2.f);
    }
    k_gemm_f<<<GEMM_BLOCKS, 256, 0, stream>>>(txP, WT0, b0, txQ, nullptr, nullptr,
                                              N_NODES, K128);
  }

  // ---- layer 2 (A in txQ, stride K256) -> f16 slot 0 of txP ----
  {
    for(int k = 1; k < KCHEB; k++){
      const _Float16* Xb = txQ + (size_t)(k - 1) * C_HID;
      const _Float16* Pb = (k >= 2) ? txQ + (size_t)(k - 2) * C_HID : nullptr;
      _Float16* tx = txQ + (size_t)k * C_HID;
      k_prop256h<<<PROP_H_BLOCKS, 256, 0, stream>>>(Xb, Pb, tx, csr_s, csr_wp, offs, perm,
                                                    k == 1 ? 1.f : 2.f);
    }
    k_gemm_f<<<GEMM_BLOCKS, 256, 0, stream>>>(txQ, WT1, b1, txP, nullptr, nullptr,
                                              N_NODES, K256);
  }

  // ---- layer 3 (A in txP, stride K256) -> pooled gsum (fused epilogue) ----
  {
    for(int k = 1; k < KCHEB; k++){
      const _Float16* Xb = txP + (size_t)(k - 1) * C_HID;
      const _Float16* Pb = (k >= 2) ? txP + (size_t)(k - 2) * C_HID : nullptr;
      _Float16* tx = txP + (size_t)k * C_HID;
      k_prop256h<<<PROP_H_BLOCKS, 256, 0, stream>>>(Xb, Pb, tx, csr_s, csr_wp, offs, perm,
                                                    k == 1 ? 1.f : 2.f);
    }
    k_gemm_f<<<GEMM_BLOCKS, 256, 0, stream>>>(txP, WT2, b2, nullptr, batch, gsum,
                                              N_NODES, K256);
  }

  k_final<<<N_GRAPHS, C_OUTC, 0, stream>>>(gsum, gcnt, Wout, bout, out);
}